// Round 9
// baseline (189.120 us; speedup 1.0000x reference)
//
#include <hip/hip_runtime.h>
#include <cstdint>
#include <cstddef>
#include <math.h>

#define CAP 4096
#define KMAX 64
#define NCHUNK 8
#define SEG 1024
#define DCUT_G1 2.5f      // first gather window below row max
#define DCUT_STORE 3.25f  // per-chunk store window (== deepest sound gather)
#define NEG_INF (-3.402823466e+38f)

// ---------------- shared device helpers ----------------

// thread-0 serial tail (f32-faithful, bit-exact vs gold since R7):
// top-k with ties of the kth scaled value, numpy pairwise-8 softmax denom,
// f32 sequential cdf vs raw f32 top_p, probs e/D. Input: sorted s_cv (desc).
__device__ __forceinline__ int tail_select(
        const float* s_cv, float* s_p, int ncand, int kwant, int topk,
        float topp) {
    int kp = 0;
    if (ncand > 0) {
        int klim = min(kwant, ncand);
        if (topk > 0 && ncand >= kwant) {
            const float kth = s_cv[kwant - 1];
            while (klim < ncand && klim < KMAX && s_cv[klim] == kth) klim++;
        }
        const float sv0 = s_cv[0];
        float e[KMAX];
        for (int j = 0; j < klim; ++j)
            e[j] = (float)exp((double)(s_cv[j] - sv0));
        float r[8] = {0.f, 0.f, 0.f, 0.f, 0.f, 0.f, 0.f, 0.f};
        for (int i = 0; i < 128; i += 8)
            #pragma unroll
            for (int j2 = 0; j2 < 8; ++j2) {
                int idx = i + j2;
                if (idx < klim) r[j2] = r[j2] + e[idx];
            }
        const float S = ((r[0] + r[1]) + (r[2] + r[3])) +
                        ((r[4] + r[5]) + (r[6] + r[7]));
        if (topp > 0.f) {
            float cdf = 0.f;
            for (int j = 0; j < klim; ++j) {
                if (j > 0 && cdf > topp) break;
                kp++;
                cdf = cdf + (float)(e[j] / S);
            }
        } else {
            kp = klim;
        }
        float D = 0.f;
        for (int j = 0; j < kp; ++j) D = D + e[j];
        if (!(D > 0.f)) D = 1.f;
        for (int j = 0; j < kp; ++j) s_p[j] = e[j] / D;
    }
    return kp;
}

// bitonic sort of s_cv/s_ci[0..sortn): value desc, index asc (stable argsort(-x))
__device__ __forceinline__ void bitonic_sort(
        float* s_cv, unsigned int* s_ci, int sortn, int tid, int nthr) {
    for (unsigned int size = 2; size <= (unsigned)sortn; size <<= 1) {
        for (unsigned int stride = size >> 1; stride > 0; stride >>= 1) {
            for (int i = tid; i < sortn / 2; i += nthr) {
                unsigned int ui = (unsigned int)i;
                unsigned int pos = 2u * ui - (ui & (stride - 1u));
                unsigned int a = pos, b = pos + stride;
                float va = s_cv[a], vb = s_cv[b];
                unsigned int ia = s_ci[a], ib = s_ci[b];
                bool aBeforeB = (va > vb) || (va == vb && ia < ib);
                bool bBeforeA = (vb > va) || (vb == va && ib < ia);
                bool descBlock = ((pos & size) == 0u);
                bool doSwap = descBlock ? bBeforeA : aBeforeB;
                if (doSwap) {
                    s_cv[a] = vb; s_cv[b] = va;
                    s_ci[a] = ib; s_ci[b] = ia;
                }
            }
            __syncthreads();
        }
    }
}

// ---------------- Kernel A: stream once ----------------
// zero output, per-chunk scaled max, speculative candidates >= chunkmax - DCUT_STORE.
// ws layout: [0, BN) u32 counts | [BN, 2*BN) f32 chunkmax | BN segs of SEG float2.
__global__ __launch_bounds__(256) void k_stream(
        const float* __restrict__ in, float* __restrict__ out,
        unsigned int* __restrict__ ws_cnt, float* __restrict__ ws_max,
        float2* __restrict__ ws_cand, const float* __restrict__ tempP,
        int nv4) {
    __shared__ float s_w[4];
    __shared__ unsigned int s_cnt;
    __shared__ float s_T;
    const int row = blockIdx.x / NCHUNK;
    const int chunk = blockIdx.x % NCHUNK;
    const int c4 = (nv4 + NCHUNK - 1) / NCHUNK;
    const int base = chunk * c4;
    const int end = min(nv4, base + c4);
    const int tid = (int)threadIdx.x;
    const float t = tempP[0];
    const bool doT = (t > 0.f);

    const float4* in4 = (const float4*)in + (size_t)row * nv4;
    float4* out4 = (float4*)out + (size_t)row * nv4;

    if (tid == 0) s_cnt = 0u;
    float m = NEG_INF;
    for (int i = base + tid; i < end; i += 256) {
        float4 v = in4[i];
        out4[i] = make_float4(0.f, 0.f, 0.f, 0.f);
        float a = doT ? v.x / t : v.x;
        float b = doT ? v.y / t : v.y;
        float c = doT ? v.z / t : v.z;
        float d = doT ? v.w / t : v.w;
        m = fmaxf(m, fmaxf(fmaxf(a, b), fmaxf(c, d)));
    }
    #pragma unroll
    for (int off = 32; off; off >>= 1)
        m = fmaxf(m, __shfl_xor(m, off));
    if ((tid & 63) == 0) s_w[tid >> 6] = m;
    __syncthreads();
    if (tid == 0) {
        float cm = fmaxf(fmaxf(s_w[0], s_w[1]), fmaxf(s_w[2], s_w[3]));
        ws_max[blockIdx.x] = cm;
        s_T = cm - DCUT_STORE;
    }
    __syncthreads();

    const float T = s_T;
    float2* seg = ws_cand + (size_t)blockIdx.x * SEG;
    for (int i = base + tid; i < end; i += 256) {
        float4 v = in4[i];  // L2-hot re-read of this block's own chunk
        float xs[4];
        xs[0] = doT ? v.x / t : v.x;
        xs[1] = doT ? v.y / t : v.y;
        xs[2] = doT ? v.z / t : v.z;
        xs[3] = doT ? v.w / t : v.w;
        #pragma unroll
        for (int c2 = 0; c2 < 4; ++c2) {
            if (xs[c2] >= T) {
                unsigned int slot = atomicAdd(&s_cnt, 1u);
                if (slot < (unsigned)SEG) {
                    float2 p;
                    p.x = xs[c2];
                    p.y = __uint_as_float((unsigned int)(4 * i + c2));
                    seg[slot] = p;
                }
            }
        }
    }
    __syncthreads();
    if (tid == 0) ws_cnt[blockIdx.x] = s_cnt;  // > SEG flags overflow
}

// ---------------- Kernel B: per-row select ----------------
__global__ __launch_bounds__(1024) void k_select(
        const float* __restrict__ in, float* __restrict__ out,
        const unsigned int* __restrict__ ws_cnt, const float* __restrict__ ws_max,
        const float2* __restrict__ ws_cand, const float* __restrict__ tempP,
        const int* __restrict__ topkP, const float* __restrict__ toppP,
        int V, int nv4) {
    __shared__ float s_cv[CAP];
    __shared__ unsigned int s_ci[CAP];
    __shared__ unsigned int s_cnt;
    __shared__ float s_p[KMAX];
    __shared__ int s_kp;

    const int row = blockIdx.x;
    const int tid = (int)threadIdx.x;
    const int nthr = (int)blockDim.x;

    const float t = tempP[0];
    const bool doT = (t > 0.f);
    int topk = topkP[0];
    if (topk < 0 || topk > V) topk = 0;
    const float topp = toppP[0];
    const int kwant = (topk > 0) ? min(topk, KMAX) : KMAX;

    // row max + overflow check from kernel A results
    float M = NEG_INF;
    bool overflow = false;
    #pragma unroll
    for (int c = 0; c < NCHUNK; ++c) {
        M = fmaxf(M, ws_max[row * NCHUNK + c]);
        if (ws_cnt[row * NCHUNK + c] > (unsigned)SEG) overflow = true;
    }

    // fast path: gather from ws with a two-step threshold ladder.
    // Sound for T >= M - DCUT_STORE: stored_c = {x >= cmax_c - DCUT_STORE}
    // and x >= T >= M - DCUT_STORE >= cmax_c - DCUT_STORE.
    unsigned int cnt = 0;
    bool ok = false;
    if (!overflow) {
        for (int attempt = 0; attempt < 2 && !ok; ++attempt) {
            const float T = M - (attempt == 0 ? DCUT_G1 : DCUT_STORE);
            __syncthreads();
            if (tid == 0) s_cnt = 0u;
            __syncthreads();
            for (int c = 0; c < NCHUNK; ++c) {
                const int cc = (int)ws_cnt[row * NCHUNK + c];
                const float2* seg = ws_cand + (size_t)(row * NCHUNK + c) * SEG;
                for (int j = tid; j < cc; j += nthr) {
                    float2 p = seg[j];
                    if (p.x >= T) {
                        unsigned int slot = atomicAdd(&s_cnt, 1u);
                        if (slot < (unsigned)CAP) {
                            s_cv[slot] = p.x;
                            s_ci[slot] = __float_as_uint(p.y);
                        }
                    }
                }
            }
            __syncthreads();
            cnt = s_cnt;
            __syncthreads();
            ok = (cnt >= (unsigned)kwant && cnt <= (unsigned)CAP);
        }
    }

    // rare fallback: full-row adaptive collection (starts wide: these rows
    // have an unusually large max-to-kth gap)
    if (!ok) {
        const float4* in4 = (const float4*)in + (size_t)row * nv4;
        float dcut = 4.5f;
        for (int round = 0; round < 14; ++round) {
            if (tid == 0) s_cnt = 0u;
            __syncthreads();
            const float T = M - dcut;
            for (int i = tid; i < nv4; i += nthr) {
                float4 v = in4[i];
                float xs[4];
                xs[0] = doT ? v.x / t : v.x;
                xs[1] = doT ? v.y / t : v.y;
                xs[2] = doT ? v.z / t : v.z;
                xs[3] = doT ? v.w / t : v.w;
                #pragma unroll
                for (int c2 = 0; c2 < 4; ++c2) {
                    if (xs[c2] >= T) {
                        unsigned int slot = atomicAdd(&s_cnt, 1u);
                        if (slot < (unsigned)CAP) {
                            s_cv[slot] = xs[c2];
                            s_ci[slot] = (unsigned int)(4 * i + c2);
                        }
                    }
                }
            }
            __syncthreads();
            cnt = s_cnt;
            __syncthreads();
            if (cnt >= (unsigned)kwant && cnt <= (unsigned)CAP) break;
            if (round == 13) break;
            dcut = (cnt < (unsigned)kwant) ? (dcut * 2.0f) : (dcut * 0.4f);
        }
    }
    const int ncand = (int)min(cnt, (unsigned)CAP);

    // dynamic sort width: smallest pow2 >= max(ncand, 128)
    int sortn = 128;
    while (sortn < ncand) sortn <<= 1;

    for (int s = ncand + tid; s < sortn; s += nthr) {
        s_cv[s] = NEG_INF;
        s_ci[s] = 0xFFFFFFFFu;
    }
    __syncthreads();

    bitonic_sort(s_cv, s_ci, sortn, tid, nthr);

    if (tid == 0) s_kp = tail_select(s_cv, s_p, ncand, kwant, topk, topp);
    __syncthreads();

    if (tid < s_kp) {
        unsigned int tok = s_ci[tid];
        if (tok < (unsigned int)V)
            out[(size_t)row * V + tok] = s_p[tid];
    }
}

// ---------------- monolithic fallback (R7-proven) for tiny ws ----------------
__global__ __launch_bounds__(1024) void k_row_mono(
        const float* __restrict__ in, float* __restrict__ out,
        const float* __restrict__ tempP, const int* __restrict__ topkP,
        const float* __restrict__ toppP, int V, int nv4) {
    __shared__ float s_red[1024];
    __shared__ float s_cv[CAP];
    __shared__ unsigned int s_ci[CAP];
    __shared__ unsigned int s_cnt;
    __shared__ float s_p[KMAX];
    __shared__ int s_kp;

    const int row = blockIdx.x;
    const int tid = (int)threadIdx.x;
    const int nthr = (int)blockDim.x;

    const float t = tempP[0];
    const bool doT = (t > 0.f);
    int topk = topkP[0];
    if (topk < 0 || topk > V) topk = 0;
    const float topp = toppP[0];

    const float4* in4 = (const float4*)in + (size_t)row * nv4;
    float4* out4 = (float4*)out + (size_t)row * nv4;
    float m = NEG_INF;
    for (int i = tid; i < nv4; i += nthr) {
        float4 v = in4[i];
        out4[i] = make_float4(0.f, 0.f, 0.f, 0.f);
        float a = doT ? v.x / t : v.x;
        float b = doT ? v.y / t : v.y;
        float c = doT ? v.z / t : v.z;
        float d = doT ? v.w / t : v.w;
        m = fmaxf(m, fmaxf(fmaxf(a, b), fmaxf(c, d)));
    }
    s_red[tid] = m;
    __syncthreads();
    for (int s = 512; s > 0; s >>= 1) {
        if (tid < s) s_red[tid] = fmaxf(s_red[tid], s_red[tid + s]);
        __syncthreads();
    }
    const float M = s_red[0];
    __syncthreads();

    const int kwant = (topk > 0) ? min(topk, KMAX) : KMAX;
    float dcut = DCUT_G1;
    unsigned int cnt = 0;
    for (int round = 0; round < 14; ++round) {
        if (tid == 0) s_cnt = 0u;
        __syncthreads();
        const float T = M - dcut;
        for (int i = tid; i < nv4; i += nthr) {
            float4 v = in4[i];
            float xs[4];
            xs[0] = doT ? v.x / t : v.x;
            xs[1] = doT ? v.y / t : v.y;
            xs[2] = doT ? v.z / t : v.z;
            xs[3] = doT ? v.w / t : v.w;
            #pragma unroll
            for (int c2 = 0; c2 < 4; ++c2) {
                if (xs[c2] >= T) {
                    unsigned int slot = atomicAdd(&s_cnt, 1u);
                    if (slot < (unsigned)CAP) {
                        s_cv[slot] = xs[c2];
                        s_ci[slot] = (unsigned int)(4 * i + c2);
                    }
                }
            }
        }
        __syncthreads();
        cnt = s_cnt;
        __syncthreads();
        if (cnt >= (unsigned)kwant && cnt <= (unsigned)CAP) break;
        if (round == 13) break;
        dcut = (cnt < (unsigned)kwant) ? (dcut * 2.0f) : (dcut * 0.4f);
    }
    const int ncand = (int)min(cnt, (unsigned)CAP);

    int sortn = 128;
    while (sortn < ncand) sortn <<= 1;
    for (int s = ncand + tid; s < sortn; s += nthr) {
        s_cv[s] = NEG_INF;
        s_ci[s] = 0xFFFFFFFFu;
    }
    __syncthreads();
    bitonic_sort(s_cv, s_ci, sortn, tid, nthr);

    if (tid == 0) s_kp = tail_select(s_cv, s_p, ncand, kwant, topk, topp);
    __syncthreads();

    if (tid < s_kp) {
        unsigned int tok = s_ci[tid];
        if (tok < (unsigned int)V)
            out[(size_t)row * V + tok] = s_p[tid];
    }
}

extern "C" void kernel_launch(void* const* d_in, const int* in_sizes, int n_in,
                              void* d_out, int out_size, void* d_ws, size_t ws_size,
                              hipStream_t stream) {
    const float* in = (const float*)d_in[0];
    const float* tempP = (const float*)d_in[2];
    const int* topkP = (const int*)d_in[3];
    const float* toppP = (const float*)d_in[4];
    float* out = (float*)d_out;

    int B = (n_in > 1 && in_sizes[1] > 0) ? in_sizes[1] : 128;
    int V = in_sizes[0] / B;
    int nv4 = V / 4;
    const int BN = B * NCHUNK;

    // ws layout: counts (BN u32) | chunkmax (BN f32) | candidates (BN*SEG float2)
    const size_t need = (size_t)BN * 4 + (size_t)BN * 4 + (size_t)BN * SEG * 8;
    if (ws_size >= need) {
        unsigned int* ws_cnt = (unsigned int*)d_ws;
        float* ws_max = (float*)((char*)d_ws + (size_t)BN * 4);
        float2* ws_cand = (float2*)((char*)d_ws + (size_t)BN * 8);
        k_stream<<<BN, 256, 0, stream>>>(in, out, ws_cnt, ws_max, ws_cand,
                                         tempP, nv4);
        k_select<<<B, 1024, 0, stream>>>(in, out, ws_cnt, ws_max, ws_cand,
                                         tempP, topkP, toppP, V, nv4);
    } else {
        k_row_mono<<<B, 1024, 0, stream>>>(in, out, tempP, topkP, toppP, V, nv4);
    }
}

// Round 11
// 138.869 us; speedup vs baseline: 1.3619x; 1.3619x over previous
//
#include <hip/hip_runtime.h>
#include <cstdint>
#include <cstddef>
#include <math.h>

#define CAP 4096
#define KMAX 64
#define NCHUNK 8
#define SEG 1024
#define DCUT_G1 2.5f      // first gather window below row max
#define DCUT_STORE 3.25f  // initial per-chunk store window (tightened on overflow)
#define NEG_INF (-3.402823466e+38f)

// ---------------- shared device helpers ----------------

// thread-0 serial tail (f32-faithful, bit-exact vs gold since R7):
// top-k with ties of the kth scaled value, numpy pairwise-8 softmax denom,
// f32 sequential cdf vs raw f32 top_p, probs e/D. Input: sorted s_cv (desc).
__device__ __forceinline__ int tail_select(
        const float* s_cv, float* s_p, int ncand, int kwant, int topk,
        float topp) {
    int kp = 0;
    if (ncand > 0) {
        int klim = min(kwant, ncand);
        if (topk > 0 && ncand >= kwant) {
            const float kth = s_cv[kwant - 1];
            while (klim < ncand && klim < KMAX && s_cv[klim] == kth) klim++;
        }
        const float sv0 = s_cv[0];
        float e[KMAX];
        for (int j = 0; j < klim; ++j)
            e[j] = (float)exp((double)(s_cv[j] - sv0));
        float r[8] = {0.f, 0.f, 0.f, 0.f, 0.f, 0.f, 0.f, 0.f};
        for (int i = 0; i < 128; i += 8)
            #pragma unroll
            for (int j2 = 0; j2 < 8; ++j2) {
                int idx = i + j2;
                if (idx < klim) r[j2] = r[j2] + e[idx];
            }
        const float S = ((r[0] + r[1]) + (r[2] + r[3])) +
                        ((r[4] + r[5]) + (r[6] + r[7]));
        if (topp > 0.f) {
            float cdf = 0.f;
            for (int j = 0; j < klim; ++j) {
                if (j > 0 && cdf > topp) break;
                kp++;
                cdf = cdf + (float)(e[j] / S);
            }
        } else {
            kp = klim;
        }
        float D = 0.f;
        for (int j = 0; j < kp; ++j) D = D + e[j];
        if (!(D > 0.f)) D = 1.f;
        for (int j = 0; j < kp; ++j) s_p[j] = e[j] / D;
    }
    return kp;
}

// bitonic sort of s_cv/s_ci[0..sortn): value desc, index asc (stable argsort(-x))
__device__ __forceinline__ void bitonic_sort(
        float* s_cv, unsigned int* s_ci, int sortn, int tid, int nthr) {
    for (unsigned int size = 2; size <= (unsigned)sortn; size <<= 1) {
        for (unsigned int stride = size >> 1; stride > 0; stride >>= 1) {
            for (int i = tid; i < sortn / 2; i += nthr) {
                unsigned int ui = (unsigned int)i;
                unsigned int pos = 2u * ui - (ui & (stride - 1u));
                unsigned int a = pos, b = pos + stride;
                float va = s_cv[a], vb = s_cv[b];
                unsigned int ia = s_ci[a], ib = s_ci[b];
                bool aBeforeB = (va > vb) || (va == vb && ia < ib);
                bool bBeforeA = (vb > va) || (vb == va && ib < ia);
                bool descBlock = ((pos & size) == 0u);
                bool doSwap = descBlock ? bBeforeA : aBeforeB;
                if (doSwap) {
                    s_cv[a] = vb; s_cv[b] = va;
                    s_ci[a] = ib; s_ci[b] = ia;
                }
            }
            __syncthreads();
        }
    }
}

// ---------------- Kernel A: stream once, adaptive per-chunk store ----------------
// zero output, per-chunk scaled max, candidates >= cmax - d with d tightened
// (x0.8, <=6 sweeps over the L3-hot own chunk) until count <= SEG.
// ws: [0,BN) u32 cnt | [BN) f32 cmax | [BN) f32 thr | BN segs of SEG float2.
__global__ __launch_bounds__(256) void k_stream(
        const float* __restrict__ in, float* __restrict__ out,
        unsigned int* __restrict__ ws_cnt, float* __restrict__ ws_max,
        float* __restrict__ ws_thr, float2* __restrict__ ws_cand,
        const float* __restrict__ tempP, int nv4) {
    __shared__ float s_w[4];
    __shared__ unsigned int s_cnt;
    __shared__ float s_cm;
    const int row = blockIdx.x / NCHUNK;
    const int chunk = blockIdx.x % NCHUNK;
    const int c4 = (nv4 + NCHUNK - 1) / NCHUNK;
    const int base = chunk * c4;
    const int end = min(nv4, base + c4);
    const int tid = (int)threadIdx.x;
    const float t = tempP[0];
    const bool doT = (t > 0.f);

    const float4* in4 = (const float4*)in + (size_t)row * nv4;
    float4* out4 = (float4*)out + (size_t)row * nv4;

    // sweep 1: zero output, chunk max
    float m = NEG_INF;
    for (int i = base + tid; i < end; i += 256) {
        float4 v = in4[i];
        out4[i] = make_float4(0.f, 0.f, 0.f, 0.f);
        float a = doT ? v.x / t : v.x;
        float b = doT ? v.y / t : v.y;
        float c = doT ? v.z / t : v.z;
        float d = doT ? v.w / t : v.w;
        m = fmaxf(m, fmaxf(fmaxf(a, b), fmaxf(c, d)));
    }
    #pragma unroll
    for (int off = 32; off; off >>= 1)
        m = fmaxf(m, __shfl_xor(m, off));
    if ((tid & 63) == 0) s_w[tid >> 6] = m;
    __syncthreads();
    if (tid == 0) {
        s_cm = fmaxf(fmaxf(s_w[0], s_w[1]), fmaxf(s_w[2], s_w[3]));
        ws_max[blockIdx.x] = s_cm;
    }
    __syncthreads();
    const float cm = s_cm;

    // adaptive store: tighten until count <= SEG
    float2* seg = ws_cand + (size_t)blockIdx.x * SEG;
    float d = DCUT_STORE;
    float T = cm - d;
    unsigned int cnt = 0;
    for (int it = 0; it < 6; ++it) {
        T = cm - d;
        __syncthreads();
        if (tid == 0) s_cnt = 0u;
        __syncthreads();
        for (int i = base + tid; i < end; i += 256) {
            float4 v = in4[i];  // L3-hot re-read of own chunk
            float xs[4];
            xs[0] = doT ? v.x / t : v.x;
            xs[1] = doT ? v.y / t : v.y;
            xs[2] = doT ? v.z / t : v.z;
            xs[3] = doT ? v.w / t : v.w;
            #pragma unroll
            for (int c2 = 0; c2 < 4; ++c2) {
                if (xs[c2] >= T) {
                    unsigned int slot = atomicAdd(&s_cnt, 1u);
                    if (slot < (unsigned)SEG) {
                        float2 p;
                        p.x = xs[c2];
                        p.y = __uint_as_float((unsigned int)(4 * i + c2));
                        seg[slot] = p;
                    }
                }
            }
        }
        __syncthreads();
        cnt = s_cnt;           // uniform
        if (cnt <= (unsigned)SEG) break;
        d *= 0.8f;
    }
    if (tid == 0) {
        ws_cnt[blockIdx.x] = cnt;   // > SEG only if 6 tightenings all overflowed
        ws_thr[blockIdx.x] = T;
    }
}

// ---------------- Kernel B: per-row select ----------------
__global__ __launch_bounds__(1024) void k_select(
        const float* __restrict__ in, float* __restrict__ out,
        const unsigned int* __restrict__ ws_cnt, const float* __restrict__ ws_max,
        const float* __restrict__ ws_thr, const float2* __restrict__ ws_cand,
        const float* __restrict__ tempP, const int* __restrict__ topkP,
        const float* __restrict__ toppP, int V, int nv4) {
    __shared__ float s_cv[CAP];
    __shared__ unsigned int s_ci[CAP];
    __shared__ unsigned int s_cnt;
    __shared__ float s_p[KMAX];
    __shared__ int s_kp;

    const int row = blockIdx.x;
    const int tid = (int)threadIdx.x;
    const int nthr = (int)blockDim.x;

    const float t = tempP[0];
    const bool doT = (t > 0.f);
    int topk = topkP[0];
    if (topk < 0 || topk > V) topk = 0;
    const float topp = toppP[0];
    const int kwant = (topk > 0) ? min(topk, KMAX) : KMAX;

    // row max, store-threshold floor, overflow check
    float M = NEG_INF;
    float Tfloor = NEG_INF;
    bool overflow = false;
    #pragma unroll
    for (int c = 0; c < NCHUNK; ++c) {
        M = fmaxf(M, ws_max[row * NCHUNK + c]);
        Tfloor = fmaxf(Tfloor, ws_thr[row * NCHUNK + c]);
        if (ws_cnt[row * NCHUNK + c] > (unsigned)SEG) overflow = true;
    }

    // fast path: gather from ws. T >= Tfloor >= every chunk's store threshold
    // => gathered set is EXACTLY {x >= T} (complete).
    unsigned int cnt = 0;
    bool ok = false;
    if (!overflow) {
        const float gs[3] = {DCUT_G1, DCUT_STORE, 1.5f};
        for (int attempt = 0; attempt < 3 && !ok; ++attempt) {
            const float T = fmaxf(M - gs[attempt], Tfloor);
            __syncthreads();
            if (tid == 0) s_cnt = 0u;
            __syncthreads();
            for (int c = 0; c < NCHUNK; ++c) {
                const int cc = (int)ws_cnt[row * NCHUNK + c];
                const float2* seg = ws_cand + (size_t)(row * NCHUNK + c) * SEG;
                for (int j = tid; j < cc; j += nthr) {
                    float2 p = seg[j];
                    if (p.x >= T) {
                        unsigned int slot = atomicAdd(&s_cnt, 1u);
                        if (slot < (unsigned)CAP) {
                            s_cv[slot] = p.x;
                            s_ci[slot] = __float_as_uint(p.y);
                        }
                    }
                }
            }
            __syncthreads();
            cnt = s_cnt;
            __syncthreads();
            ok = (cnt >= (unsigned)kwant && cnt <= (unsigned)CAP);
        }
    }

    // rare fallback: full-row adaptive collection, seeded by failure mode
    if (!ok) {
        const float4* in4 = (const float4*)in + (size_t)row * nv4;
        float dcut = (cnt > (unsigned)CAP) ? 1.0f : 4.5f;
        for (int round = 0; round < 14; ++round) {
            if (tid == 0) s_cnt = 0u;
            __syncthreads();
            const float T = M - dcut;
            for (int i = tid; i < nv4; i += nthr) {
                float4 v = in4[i];
                float xs[4];
                xs[0] = doT ? v.x / t : v.x;
                xs[1] = doT ? v.y / t : v.y;
                xs[2] = doT ? v.z / t : v.z;
                xs[3] = doT ? v.w / t : v.w;
                #pragma unroll
                for (int c2 = 0; c2 < 4; ++c2) {
                    if (xs[c2] >= T) {
                        unsigned int slot = atomicAdd(&s_cnt, 1u);
                        if (slot < (unsigned)CAP) {
                            s_cv[slot] = xs[c2];
                            s_ci[slot] = (unsigned int)(4 * i + c2);
                        }
                    }
                }
            }
            __syncthreads();
            cnt = s_cnt;
            __syncthreads();
            if (cnt >= (unsigned)kwant && cnt <= (unsigned)CAP) break;
            if (round == 13) break;
            dcut = (cnt < (unsigned)kwant) ? (dcut * 2.0f) : (dcut * 0.4f);
        }
    }
    const int ncand = (int)min(cnt, (unsigned)CAP);

    // dynamic sort width: smallest pow2 >= max(ncand, 128)
    int sortn = 128;
    while (sortn < ncand) sortn <<= 1;

    for (int s = ncand + tid; s < sortn; s += nthr) {
        s_cv[s] = NEG_INF;
        s_ci[s] = 0xFFFFFFFFu;
    }
    __syncthreads();

    bitonic_sort(s_cv, s_ci, sortn, tid, nthr);

    if (tid == 0) s_kp = tail_select(s_cv, s_p, ncand, kwant, topk, topp);
    __syncthreads();

    if (tid < s_kp) {
        unsigned int tok = s_ci[tid];
        if (tok < (unsigned int)V)
            out[(size_t)row * V + tok] = s_p[tid];
    }
}

// ---------------- monolithic fallback (R7-proven) for tiny ws ----------------
__global__ __launch_bounds__(1024) void k_row_mono(
        const float* __restrict__ in, float* __restrict__ out,
        const float* __restrict__ tempP, const int* __restrict__ topkP,
        const float* __restrict__ toppP, int V, int nv4) {
    __shared__ float s_red[1024];
    __shared__ float s_cv[CAP];
    __shared__ unsigned int s_ci[CAP];
    __shared__ unsigned int s_cnt;
    __shared__ float s_p[KMAX];
    __shared__ int s_kp;

    const int row = blockIdx.x;
    const int tid = (int)threadIdx.x;
    const int nthr = (int)blockDim.x;

    const float t = tempP[0];
    const bool doT = (t > 0.f);
    int topk = topkP[0];
    if (topk < 0 || topk > V) topk = 0;
    const float topp = toppP[0];

    const float4* in4 = (const float4*)in + (size_t)row * nv4;
    float4* out4 = (float4*)out + (size_t)row * nv4;
    float m = NEG_INF;
    for (int i = tid; i < nv4; i += nthr) {
        float4 v = in4[i];
        out4[i] = make_float4(0.f, 0.f, 0.f, 0.f);
        float a = doT ? v.x / t : v.x;
        float b = doT ? v.y / t : v.y;
        float c = doT ? v.z / t : v.z;
        float d = doT ? v.w / t : v.w;
        m = fmaxf(m, fmaxf(fmaxf(a, b), fmaxf(c, d)));
    }
    s_red[tid] = m;
    __syncthreads();
    for (int s = 512; s > 0; s >>= 1) {
        if (tid < s) s_red[tid] = fmaxf(s_red[tid], s_red[tid + s]);
        __syncthreads();
    }
    const float M = s_red[0];
    __syncthreads();

    const int kwant = (topk > 0) ? min(topk, KMAX) : KMAX;
    float dcut = DCUT_G1;
    unsigned int cnt = 0;
    for (int round = 0; round < 14; ++round) {
        if (tid == 0) s_cnt = 0u;
        __syncthreads();
        const float T = M - dcut;
        for (int i = tid; i < nv4; i += nthr) {
            float4 v = in4[i];
            float xs[4];
            xs[0] = doT ? v.x / t : v.x;
            xs[1] = doT ? v.y / t : v.y;
            xs[2] = doT ? v.z / t : v.z;
            xs[3] = doT ? v.w / t : v.w;
            #pragma unroll
            for (int c2 = 0; c2 < 4; ++c2) {
                if (xs[c2] >= T) {
                    unsigned int slot = atomicAdd(&s_cnt, 1u);
                    if (slot < (unsigned)CAP) {
                        s_cv[slot] = xs[c2];
                        s_ci[slot] = (unsigned int)(4 * i + c2);
                    }
                }
            }
        }
        __syncthreads();
        cnt = s_cnt;
        __syncthreads();
        if (cnt >= (unsigned)kwant && cnt <= (unsigned)CAP) break;
        if (round == 13) break;
        dcut = (cnt < (unsigned)kwant) ? (dcut * 2.0f) : (dcut * 0.4f);
    }
    const int ncand = (int)min(cnt, (unsigned)CAP);

    int sortn = 128;
    while (sortn < ncand) sortn <<= 1;
    for (int s = ncand + tid; s < sortn; s += nthr) {
        s_cv[s] = NEG_INF;
        s_ci[s] = 0xFFFFFFFFu;
    }
    __syncthreads();
    bitonic_sort(s_cv, s_ci, sortn, tid, nthr);

    if (tid == 0) s_kp = tail_select(s_cv, s_p, ncand, kwant, topk, topp);
    __syncthreads();

    if (tid < s_kp) {
        unsigned int tok = s_ci[tid];
        if (tok < (unsigned int)V)
            out[(size_t)row * V + tok] = s_p[tid];
    }
}

extern "C" void kernel_launch(void* const* d_in, const int* in_sizes, int n_in,
                              void* d_out, int out_size, void* d_ws, size_t ws_size,
                              hipStream_t stream) {
    const float* in = (const float*)d_in[0];
    const float* tempP = (const float*)d_in[2];
    const int* topkP = (const int*)d_in[3];
    const float* toppP = (const float*)d_in[4];
    float* out = (float*)d_out;

    int B = (n_in > 1 && in_sizes[1] > 0) ? in_sizes[1] : 128;
    int V = in_sizes[0] / B;
    int nv4 = V / 4;
    const int BN = B * NCHUNK;

    // ws: cnt (BN u32) | cmax (BN f32) | thr (BN f32) | cand (BN*SEG float2)
    const size_t need = (size_t)BN * 12 + (size_t)BN * SEG * 8;
    if (ws_size >= need) {
        unsigned int* ws_cnt = (unsigned int*)d_ws;
        float* ws_max = (float*)((char*)d_ws + (size_t)BN * 4);
        float* ws_thr = (float*)((char*)d_ws + (size_t)BN * 8);
        float2* ws_cand = (float2*)((char*)d_ws + (size_t)BN * 12);
        k_stream<<<BN, 256, 0, stream>>>(in, out, ws_cnt, ws_max, ws_thr,
                                         ws_cand, tempP, nv4);
        k_select<<<B, 1024, 0, stream>>>(in, out, ws_cnt, ws_max, ws_thr,
                                         ws_cand, tempP, topkP, toppP, V, nv4);
    } else {
        k_row_mono<<<B, 1024, 0, stream>>>(in, out, tempP, topkP, toppP, V, nv4);
    }
}

// Round 12
// 129.142 us; speedup vs baseline: 1.4644x; 1.0753x over previous
//
#include <hip/hip_runtime.h>
#include <cstdint>
#include <cstddef>
#include <math.h>

#define CAP 4096
#define KMAX 64
#define NCHUNK 8
#define SEG 1024
#define MINSTORE 64
#define NEG_INF (-3.402823466e+38f)

typedef float v4f __attribute__((ext_vector_type(4)));

// margin covering f32 div rounding at threshold boundaries (scaled-tie safety)
__device__ __forceinline__ float dmarg(float T) {
    return fabsf(T) * 6e-7f + 1e-30f;
}

// ---------------- shared device helpers ----------------

// thread-0 serial tail (f32-faithful, bit-exact vs gold since R7):
// top-k with ties of the kth scaled value, numpy pairwise-8 softmax denom,
// f32 sequential cdf vs raw f32 top_p, probs e/D. Input: sorted SCALED s_cv.
__device__ __forceinline__ int tail_select(
        const float* s_cv, float* s_p, int ncand, int kwant, int topk,
        float topp) {
    int kp = 0;
    if (ncand > 0) {
        int klim = min(kwant, ncand);
        if (topk > 0 && ncand >= kwant) {
            const float kth = s_cv[kwant - 1];
            while (klim < ncand && klim < KMAX && s_cv[klim] == kth) klim++;
        }
        const float sv0 = s_cv[0];
        float e[KMAX];
        for (int j = 0; j < klim; ++j)
            e[j] = (float)exp((double)(s_cv[j] - sv0));
        float r[8] = {0.f, 0.f, 0.f, 0.f, 0.f, 0.f, 0.f, 0.f};
        for (int i = 0; i < 128; i += 8)
            #pragma unroll
            for (int j2 = 0; j2 < 8; ++j2) {
                int idx = i + j2;
                if (idx < klim) r[j2] = r[j2] + e[idx];
            }
        const float S = ((r[0] + r[1]) + (r[2] + r[3])) +
                        ((r[4] + r[5]) + (r[6] + r[7]));
        if (topp > 0.f) {
            float cdf = 0.f;
            for (int j = 0; j < klim; ++j) {
                if (j > 0 && cdf > topp) break;
                kp++;
                cdf = cdf + (float)(e[j] / S);
            }
        } else {
            kp = klim;
        }
        float D = 0.f;
        for (int j = 0; j < kp; ++j) D = D + e[j];
        if (!(D > 0.f)) D = 1.f;
        for (int j = 0; j < kp; ++j) s_p[j] = e[j] / D;
    }
    return kp;
}

// bitonic sort of s_cv/s_ci[0..sortn): value desc, index asc (stable argsort(-x))
__device__ __forceinline__ void bitonic_sort(
        float* s_cv, unsigned int* s_ci, int sortn, int tid, int nthr) {
    for (unsigned int size = 2; size <= (unsigned)sortn; size <<= 1) {
        for (unsigned int stride = size >> 1; stride > 0; stride >>= 1) {
            for (int i = tid; i < sortn / 2; i += nthr) {
                unsigned int ui = (unsigned int)i;
                unsigned int pos = 2u * ui - (ui & (stride - 1u));
                unsigned int a = pos, b = pos + stride;
                float va = s_cv[a], vb = s_cv[b];
                unsigned int ia = s_ci[a], ib = s_ci[b];
                bool aBeforeB = (va > vb) || (va == vb && ia < ib);
                bool bBeforeA = (vb > va) || (vb == va && ib < ia);
                bool descBlock = ((pos & size) == 0u);
                bool doSwap = descBlock ? bBeforeA : aBeforeB;
                if (doSwap) {
                    s_cv[a] = vb; s_cv[b] = va;
                    s_ci[a] = ib; s_ci[b] = ia;
                }
            }
            __syncthreads();
        }
    }
}

// ---------------- Kernel A: stream once (ILP-4), adaptive per-chunk store ----
// ALL in ORIGINAL space (monotone /t deferred to k_select). Sweep 1: zero
// output (nontemporal) + chunk max. Sweep 2 (L2/L3-hot): collect
// {x >= cmax - d}; tighten d (x0.8) while cnt > SEG, loosen (x1.6) while
// cnt < MINSTORE — guarantees every chunk stores >= MINSTORE candidates.
__global__ __launch_bounds__(256) void k_stream(
        const float* __restrict__ in, float* __restrict__ out,
        unsigned int* __restrict__ ws_cnt, float* __restrict__ ws_max,
        float* __restrict__ ws_thr, float2* __restrict__ ws_cand,
        const float* __restrict__ tempP, int nv4) {
    __shared__ float s_w[4];
    __shared__ unsigned int s_cnt;
    __shared__ float s_cm;
    const int row = blockIdx.x / NCHUNK;
    const int chunk = blockIdx.x % NCHUNK;
    const int c4 = (nv4 + NCHUNK - 1) / NCHUNK;
    const int base = chunk * c4;
    const int end = min(nv4, base + c4);
    const int tid = (int)threadIdx.x;
    const float t = tempP[0];
    const bool doT = (t > 0.f);
    const float tt = doT ? t : 1.f;

    const float4* in4 = (const float4*)in + (size_t)row * nv4;
    float4* out4 = (float4*)out + (size_t)row * nv4;

    // ---- sweep 1: zero output + chunk max, 4 loads in flight ----
    float m = NEG_INF;
    const v4f z4 = {0.f, 0.f, 0.f, 0.f};
    int i = base + tid;
    for (; i + 768 < end; i += 1024) {
        float4 v0 = in4[i];
        float4 v1 = in4[i + 256];
        float4 v2 = in4[i + 512];
        float4 v3 = in4[i + 768];
        __builtin_nontemporal_store(z4, (v4f*)(out4 + i));
        __builtin_nontemporal_store(z4, (v4f*)(out4 + i + 256));
        __builtin_nontemporal_store(z4, (v4f*)(out4 + i + 512));
        __builtin_nontemporal_store(z4, (v4f*)(out4 + i + 768));
        float m0 = fmaxf(fmaxf(v0.x, v0.y), fmaxf(v0.z, v0.w));
        float m1 = fmaxf(fmaxf(v1.x, v1.y), fmaxf(v1.z, v1.w));
        float m2 = fmaxf(fmaxf(v2.x, v2.y), fmaxf(v2.z, v2.w));
        float m3 = fmaxf(fmaxf(v3.x, v3.y), fmaxf(v3.z, v3.w));
        m = fmaxf(m, fmaxf(fmaxf(m0, m1), fmaxf(m2, m3)));
    }
    for (; i < end; i += 256) {
        float4 v = in4[i];
        __builtin_nontemporal_store(z4, (v4f*)(out4 + i));
        m = fmaxf(m, fmaxf(fmaxf(v.x, v.y), fmaxf(v.z, v.w)));
    }
    #pragma unroll
    for (int off = 32; off; off >>= 1)
        m = fmaxf(m, __shfl_xor(m, off));
    if ((tid & 63) == 0) s_w[tid >> 6] = m;
    __syncthreads();
    if (tid == 0) {
        s_cm = fmaxf(fmaxf(s_w[0], s_w[1]), fmaxf(s_w[2], s_w[3]));
        ws_max[blockIdx.x] = s_cm;
    }
    __syncthreads();
    const float cm = s_cm;

    // ---- sweep 2: adaptive collect (cache-hot re-read of own chunk) ----
    float2* seg = ws_cand + (size_t)blockIdx.x * SEG;
    float d = 3.25f * tt;
    float T = cm - d;
    unsigned int cnt = 0;
    const int nelem = (end - base) * 4;
    for (int it = 0; it < 8; ++it) {
        T = cm - d;
        __syncthreads();
        if (tid == 0) s_cnt = 0u;
        __syncthreads();
        int j = base + tid;
        for (; j + 768 < end; j += 1024) {
            float4 v0 = in4[j];
            float4 v1 = in4[j + 256];
            float4 v2 = in4[j + 512];
            float4 v3 = in4[j + 768];
            const float4 vv[4] = {v0, v1, v2, v3};
            #pragma unroll
            for (int u = 0; u < 4; ++u) {
                const float xs[4] = {vv[u].x, vv[u].y, vv[u].z, vv[u].w};
                #pragma unroll
                for (int c2 = 0; c2 < 4; ++c2) {
                    if (xs[c2] >= T) {
                        unsigned int slot = atomicAdd(&s_cnt, 1u);
                        if (slot < (unsigned)SEG) {
                            float2 p;
                            p.x = xs[c2];
                            p.y = __uint_as_float((unsigned)(4 * (j + u * 256) + c2));
                            seg[slot] = p;
                        }
                    }
                }
            }
        }
        for (; j < end; j += 256) {
            float4 v = in4[j];
            const float xs[4] = {v.x, v.y, v.z, v.w};
            #pragma unroll
            for (int c2 = 0; c2 < 4; ++c2) {
                if (xs[c2] >= T) {
                    unsigned int slot = atomicAdd(&s_cnt, 1u);
                    if (slot < (unsigned)SEG) {
                        float2 p;
                        p.x = xs[c2];
                        p.y = __uint_as_float((unsigned)(4 * j + c2));
                        seg[slot] = p;
                    }
                }
            }
        }
        __syncthreads();
        cnt = s_cnt;
        __syncthreads();
        if (cnt > (unsigned)SEG)      { if (it < 7) { d *= 0.8f; continue; } break; }
        if (cnt < (unsigned)MINSTORE && nelem > MINSTORE)
                                      { if (it < 7) { d *= 1.6f; continue; } break; }
        break;
    }
    if (tid == 0) {
        ws_cnt[blockIdx.x] = cnt;                   // > SEG flags overflow
        ws_thr[blockIdx.x] = T + 2.f * dmarg(T);    // recorded floor (upper-biased)
    }
}

// ---------------- Kernel B: per-row select ----------------
__global__ __launch_bounds__(1024) void k_select(
        const float* __restrict__ in, float* __restrict__ out,
        const unsigned int* __restrict__ ws_cnt, const float* __restrict__ ws_max,
        const float* __restrict__ ws_thr, const float2* __restrict__ ws_cand,
        const float* __restrict__ tempP, const int* __restrict__ topkP,
        const float* __restrict__ toppP, int V, int nv4) {
    __shared__ float s_cv[CAP];
    __shared__ unsigned int s_ci[CAP];
    __shared__ unsigned int s_cnt;
    __shared__ float s_p[KMAX];
    __shared__ int s_kp;

    const int row = blockIdx.x;
    const int tid = (int)threadIdx.x;
    const int nthr = (int)blockDim.x;

    const float t = tempP[0];
    const bool doT = (t > 0.f);
    const float tt = doT ? t : 1.f;
    int topk = topkP[0];
    if (topk < 0 || topk > V) topk = 0;
    const float topp = toppP[0];
    const int kwant = (topk > 0) ? min(topk, KMAX) : KMAX;

    // row max, recorded-threshold floor, overflow check (all original space)
    float M = NEG_INF;
    float Tfloor = NEG_INF;
    bool overflow = false;
    #pragma unroll
    for (int c = 0; c < NCHUNK; ++c) {
        M = fmaxf(M, ws_max[row * NCHUNK + c]);
        Tfloor = fmaxf(Tfloor, ws_thr[row * NCHUNK + c]);
        if (ws_cnt[row * NCHUNK + c] > (unsigned)SEG) overflow = true;
    }

    // gather ladder; attempt 2 (= Tfloor) is GUARANTEED >= MINSTORE candidates
    unsigned int cnt = 0;
    bool ok = false;
    if (!overflow) {
        for (int attempt = 0; attempt < 3 && !ok; ++attempt) {
            const float T_att = (attempt == 0) ? fmaxf(M - 2.5f * tt, Tfloor)
                              : (attempt == 1) ? fmaxf(M - 3.25f * tt, Tfloor)
                              : Tfloor;
            const float Tcmp = T_att - dmarg(T_att);
            __syncthreads();
            if (tid == 0) s_cnt = 0u;
            __syncthreads();
            for (int c = 0; c < NCHUNK; ++c) {
                const int cc = (int)ws_cnt[row * NCHUNK + c];
                const float2* seg = ws_cand + (size_t)(row * NCHUNK + c) * SEG;
                for (int j = tid; j < cc; j += nthr) {
                    float2 p = seg[j];
                    if (p.x >= Tcmp) {
                        unsigned int slot = atomicAdd(&s_cnt, 1u);
                        if (slot < (unsigned)CAP) {
                            s_cv[slot] = p.x;
                            s_ci[slot] = __float_as_uint(p.y);
                        }
                    }
                }
            }
            __syncthreads();
            cnt = s_cnt;
            __syncthreads();
            ok = (cnt >= (unsigned)kwant && cnt <= (unsigned)CAP);
        }
    }

    // safety net (structurally unreachable now): full-row adaptive collect
    if (!ok) {
        const float4* in4 = (const float4*)in + (size_t)row * nv4;
        float dcut = (cnt > (unsigned)CAP) ? 1.0f * tt : 4.5f * tt;
        for (int round = 0; round < 14; ++round) {
            if (tid == 0) s_cnt = 0u;
            __syncthreads();
            const float T = M - dcut;
            for (int i = tid; i < nv4; i += nthr) {
                float4 v = in4[i];
                const float xs[4] = {v.x, v.y, v.z, v.w};
                #pragma unroll
                for (int c2 = 0; c2 < 4; ++c2) {
                    if (xs[c2] >= T) {
                        unsigned int slot = atomicAdd(&s_cnt, 1u);
                        if (slot < (unsigned)CAP) {
                            s_cv[slot] = xs[c2];
                            s_ci[slot] = (unsigned int)(4 * i + c2);
                        }
                    }
                }
            }
            __syncthreads();
            cnt = s_cnt;
            __syncthreads();
            if (cnt >= (unsigned)kwant && cnt <= (unsigned)CAP) break;
            if (round == 13) break;
            dcut = (cnt < (unsigned)kwant) ? (dcut * 2.0f) : (dcut * 0.4f);
        }
    }
    const int ncand = (int)min(cnt, (unsigned)CAP);

    // convert to SCALED space (identical f32 division as numpy, per element)
    if (doT) {
        for (int j = tid; j < ncand; j += nthr) s_cv[j] = s_cv[j] / t;
    }

    // dynamic sort width: smallest pow2 >= max(ncand, 128)
    int sortn = 128;
    while (sortn < ncand) sortn <<= 1;
    for (int s = ncand + tid; s < sortn; s += nthr) {
        s_cv[s] = NEG_INF;
        s_ci[s] = 0xFFFFFFFFu;
    }
    __syncthreads();

    bitonic_sort(s_cv, s_ci, sortn, tid, nthr);

    if (tid == 0) s_kp = tail_select(s_cv, s_p, ncand, kwant, topk, topp);
    __syncthreads();

    if (tid < s_kp) {
        unsigned int tok = s_ci[tid];
        if (tok < (unsigned int)V)
            out[(size_t)row * V + tok] = s_p[tid];
    }
}

// ---------------- monolithic fallback (R7-proven, scaled space) ----------------
__global__ __launch_bounds__(1024) void k_row_mono(
        const float* __restrict__ in, float* __restrict__ out,
        const float* __restrict__ tempP, const int* __restrict__ topkP,
        const float* __restrict__ toppP, int V, int nv4) {
    __shared__ float s_red[1024];
    __shared__ float s_cv[CAP];
    __shared__ unsigned int s_ci[CAP];
    __shared__ unsigned int s_cnt;
    __shared__ float s_p[KMAX];
    __shared__ int s_kp;

    const int row = blockIdx.x;
    const int tid = (int)threadIdx.x;
    const int nthr = (int)blockDim.x;

    const float t = tempP[0];
    const bool doT = (t > 0.f);
    int topk = topkP[0];
    if (topk < 0 || topk > V) topk = 0;
    const float topp = toppP[0];

    const float4* in4 = (const float4*)in + (size_t)row * nv4;
    float4* out4 = (float4*)out + (size_t)row * nv4;
    float m = NEG_INF;
    for (int i = tid; i < nv4; i += nthr) {
        float4 v = in4[i];
        out4[i] = make_float4(0.f, 0.f, 0.f, 0.f);
        float a = doT ? v.x / t : v.x;
        float b = doT ? v.y / t : v.y;
        float c = doT ? v.z / t : v.z;
        float d = doT ? v.w / t : v.w;
        m = fmaxf(m, fmaxf(fmaxf(a, b), fmaxf(c, d)));
    }
    s_red[tid] = m;
    __syncthreads();
    for (int s = 512; s > 0; s >>= 1) {
        if (tid < s) s_red[tid] = fmaxf(s_red[tid], s_red[tid + s]);
        __syncthreads();
    }
    const float M = s_red[0];
    __syncthreads();

    const int kwant = (topk > 0) ? min(topk, KMAX) : KMAX;
    float dcut = 2.5f;
    unsigned int cnt = 0;
    for (int round = 0; round < 14; ++round) {
        if (tid == 0) s_cnt = 0u;
        __syncthreads();
        const float T = M - dcut;
        for (int i = tid; i < nv4; i += nthr) {
            float4 v = in4[i];
            float xs[4];
            xs[0] = doT ? v.x / t : v.x;
            xs[1] = doT ? v.y / t : v.y;
            xs[2] = doT ? v.z / t : v.z;
            xs[3] = doT ? v.w / t : v.w;
            #pragma unroll
            for (int c2 = 0; c2 < 4; ++c2) {
                if (xs[c2] >= T) {
                    unsigned int slot = atomicAdd(&s_cnt, 1u);
                    if (slot < (unsigned)CAP) {
                        s_cv[slot] = xs[c2];
                        s_ci[slot] = (unsigned int)(4 * i + c2);
                    }
                }
            }
        }
        __syncthreads();
        cnt = s_cnt;
        __syncthreads();
        if (cnt >= (unsigned)kwant && cnt <= (unsigned)CAP) break;
        if (round == 13) break;
        dcut = (cnt < (unsigned)kwant) ? (dcut * 2.0f) : (dcut * 0.4f);
    }
    const int ncand = (int)min(cnt, (unsigned)CAP);

    int sortn = 128;
    while (sortn < ncand) sortn <<= 1;
    for (int s = ncand + tid; s < sortn; s += nthr) {
        s_cv[s] = NEG_INF;
        s_ci[s] = 0xFFFFFFFFu;
    }
    __syncthreads();
    bitonic_sort(s_cv, s_ci, sortn, tid, nthr);

    if (tid == 0) s_kp = tail_select(s_cv, s_p, ncand, kwant, topk, topp);
    __syncthreads();

    if (tid < s_kp) {
        unsigned int tok = s_ci[tid];
        if (tok < (unsigned int)V)
            out[(size_t)row * V + tok] = s_p[tid];
    }
}

extern "C" void kernel_launch(void* const* d_in, const int* in_sizes, int n_in,
                              void* d_out, int out_size, void* d_ws, size_t ws_size,
                              hipStream_t stream) {
    const float* in = (const float*)d_in[0];
    const float* tempP = (const float*)d_in[2];
    const int* topkP = (const int*)d_in[3];
    const float* toppP = (const float*)d_in[4];
    float* out = (float*)d_out;

    int B = (n_in > 1 && in_sizes[1] > 0) ? in_sizes[1] : 128;
    int V = in_sizes[0] / B;
    int nv4 = V / 4;
    const int BN = B * NCHUNK;

    // ws: cnt (BN u32) | cmax (BN f32) | thr (BN f32) | cand (BN*SEG float2)
    const size_t need = (size_t)BN * 12 + (size_t)BN * SEG * 8;
    if (ws_size >= need) {
        unsigned int* ws_cnt = (unsigned int*)d_ws;
        float* ws_max = (float*)((char*)d_ws + (size_t)BN * 4);
        float* ws_thr = (float*)((char*)d_ws + (size_t)BN * 8);
        float2* ws_cand = (float2*)((char*)d_ws + (size_t)BN * 12);
        k_stream<<<BN, 256, 0, stream>>>(in, out, ws_cnt, ws_max, ws_thr,
                                         ws_cand, tempP, nv4);
        k_select<<<B, 1024, 0, stream>>>(in, out, ws_cnt, ws_max, ws_thr,
                                         ws_cand, tempP, topkP, toppP, V, nv4);
    } else {
        k_row_mono<<<B, 1024, 0, stream>>>(in, out, tempP, topkP, toppP, V, nv4);
    }
}

// Round 13
// 91.342 us; speedup vs baseline: 2.0705x; 1.4138x over previous
//
#include <hip/hip_runtime.h>
#include <cstdint>
#include <cstddef>
#include <math.h>

#define CAP 4096
#define KMAX 64
#define NCHUNK 16
#define SEG 512
#define MINSTORE 64
#define NEG_INF (-3.402823466e+38f)

typedef float v4f __attribute__((ext_vector_type(4)));
typedef unsigned long long ull;

// monotonic bijective f32 <-> u32 order keys
__device__ __forceinline__ unsigned int fkey(float f) {
    unsigned int u = __float_as_uint(f);
    return (u & 0x80000000u) ? ~u : (u | 0x80000000u);
}
__device__ __forceinline__ float unkey(unsigned int k) {
    unsigned int u = (k & 0x80000000u) ? (k & 0x7FFFFFFFu) : ~k;
    return __uint_as_float(u);
}

// margin covering f32 div rounding at threshold boundaries (scaled-tie safety)
__device__ __forceinline__ float dmarg(float T) {
    return fabsf(T) * 6e-7f + 1e-30f;
}

// ---- wave-level bitonic primitives (64 lanes, u64 keys, DESC) ----
// full sort of 64 keys (one/lane), descending
__device__ __forceinline__ ull sort64_desc(ull key, int lane) {
    #pragma unroll
    for (int size = 2; size <= 64; size <<= 1) {
        #pragma unroll
        for (int stride = size >> 1; stride > 0; stride >>= 1) {
            ull other = __shfl_xor(key, stride, 64);
            bool lower = ((lane & stride) == 0);
            bool descBlk = ((lane & size) == 0);
            bool keepMax = (descBlk == lower);
            bool gt = key > other;
            key = (keepMax == gt) ? key : other;
        }
    }
    return key;
}
// clean a bitonic sequence to descending order
__device__ __forceinline__ ull clean64_desc(ull key, int lane) {
    #pragma unroll
    for (int stride = 32; stride > 0; stride >>= 1) {
        ull other = __shfl_xor(key, stride, 64);
        bool lower = ((lane & stride) == 0);
        bool gt = key > other;
        key = (lower == gt) ? key : other;  // lower lane keeps max
    }
    return key;
}

// ---------------- shared device helpers ----------------

// thread-0 serial tail (f32-faithful, bit-exact vs gold since R7):
// top-k with ties of the kth scaled value, numpy pairwise-8 softmax denom,
// f32 sequential cdf vs raw f32 top_p, probs e/D. Input: sorted SCALED s_cv.
__device__ __forceinline__ int tail_select(
        const float* s_cv, float* s_p, int ncand, int kwant, int topk,
        float topp) {
    int kp = 0;
    if (ncand > 0) {
        int klim = min(kwant, ncand);
        if (topk > 0 && ncand >= kwant) {
            const float kth = s_cv[kwant - 1];
            while (klim < ncand && klim < KMAX && s_cv[klim] == kth) klim++;
        }
        const float sv0 = s_cv[0];
        float e[KMAX];
        for (int j = 0; j < klim; ++j)
            e[j] = (float)exp((double)(s_cv[j] - sv0));
        float r[8] = {0.f, 0.f, 0.f, 0.f, 0.f, 0.f, 0.f, 0.f};
        for (int i = 0; i < 128; i += 8)
            #pragma unroll
            for (int j2 = 0; j2 < 8; ++j2) {
                int idx = i + j2;
                if (idx < klim) r[j2] = r[j2] + e[idx];
            }
        const float S = ((r[0] + r[1]) + (r[2] + r[3])) +
                        ((r[4] + r[5]) + (r[6] + r[7]));
        if (topp > 0.f) {
            float cdf = 0.f;
            for (int j = 0; j < klim; ++j) {
                if (j > 0 && cdf > topp) break;
                kp++;
                cdf = cdf + (float)(e[j] / S);
            }
        } else {
            kp = klim;
        }
        float D = 0.f;
        for (int j = 0; j < kp; ++j) D = D + e[j];
        if (!(D > 0.f)) D = 1.f;
        for (int j = 0; j < kp; ++j) s_p[j] = e[j] / D;
    }
    return kp;
}

// LDS bitonic sort (mono fallback only): value desc, index asc
__device__ __forceinline__ void bitonic_sort(
        float* s_cv, unsigned int* s_ci, int sortn, int tid, int nthr) {
    for (unsigned int size = 2; size <= (unsigned)sortn; size <<= 1) {
        for (unsigned int stride = size >> 1; stride > 0; stride >>= 1) {
            for (int i = tid; i < sortn / 2; i += nthr) {
                unsigned int ui = (unsigned int)i;
                unsigned int pos = 2u * ui - (ui & (stride - 1u));
                unsigned int a = pos, b = pos + stride;
                float va = s_cv[a], vb = s_cv[b];
                unsigned int ia = s_ci[a], ib = s_ci[b];
                bool aBeforeB = (va > vb) || (va == vb && ia < ib);
                bool bBeforeA = (vb > va) || (vb == va && ib < ia);
                bool descBlock = ((pos & size) == 0u);
                bool doSwap = descBlock ? bBeforeA : aBeforeB;
                if (doSwap) {
                    s_cv[a] = vb; s_cv[b] = va;
                    s_ci[a] = ib; s_ci[b] = ia;
                }
            }
            __syncthreads();
        }
    }
}

// ---------------- Kernel A: stream once (ILP-4), adaptive per-chunk store ----
// ORIGINAL space (monotone /t deferred). Sweep 1: zero output (nontemporal)
// + chunk max. Sweep 2 (L3-hot): collect {x >= cmax - d}; tighten d (x0.8)
// while cnt > SEG, loosen (x1.6) while cnt < MINSTORE.
__global__ __launch_bounds__(256) void k_stream(
        const float* __restrict__ in, float* __restrict__ out,
        unsigned int* __restrict__ ws_cnt, float* __restrict__ ws_max,
        float* __restrict__ ws_thr, float2* __restrict__ ws_cand,
        const float* __restrict__ tempP, int nv4) {
    __shared__ float s_w[4];
    __shared__ unsigned int s_cnt;
    __shared__ float s_cm;
    const int row = blockIdx.x / NCHUNK;
    const int chunk = blockIdx.x % NCHUNK;
    const int c4 = (nv4 + NCHUNK - 1) / NCHUNK;
    const int base = chunk * c4;
    const int end = min(nv4, base + c4);
    const int tid = (int)threadIdx.x;
    const float t = tempP[0];
    const bool doT = (t > 0.f);
    const float tt = doT ? t : 1.f;

    const float4* in4 = (const float4*)in + (size_t)row * nv4;
    float4* out4 = (float4*)out + (size_t)row * nv4;

    // ---- sweep 1: zero output + chunk max, 4 loads in flight ----
    float m = NEG_INF;
    const v4f z4 = {0.f, 0.f, 0.f, 0.f};
    int i = base + tid;
    for (; i + 768 < end; i += 1024) {
        float4 v0 = in4[i];
        float4 v1 = in4[i + 256];
        float4 v2 = in4[i + 512];
        float4 v3 = in4[i + 768];
        __builtin_nontemporal_store(z4, (v4f*)(out4 + i));
        __builtin_nontemporal_store(z4, (v4f*)(out4 + i + 256));
        __builtin_nontemporal_store(z4, (v4f*)(out4 + i + 512));
        __builtin_nontemporal_store(z4, (v4f*)(out4 + i + 768));
        float m0 = fmaxf(fmaxf(v0.x, v0.y), fmaxf(v0.z, v0.w));
        float m1 = fmaxf(fmaxf(v1.x, v1.y), fmaxf(v1.z, v1.w));
        float m2 = fmaxf(fmaxf(v2.x, v2.y), fmaxf(v2.z, v2.w));
        float m3 = fmaxf(fmaxf(v3.x, v3.y), fmaxf(v3.z, v3.w));
        m = fmaxf(m, fmaxf(fmaxf(m0, m1), fmaxf(m2, m3)));
    }
    for (; i < end; i += 256) {
        float4 v = in4[i];
        __builtin_nontemporal_store(z4, (v4f*)(out4 + i));
        m = fmaxf(m, fmaxf(fmaxf(v.x, v.y), fmaxf(v.z, v.w)));
    }
    #pragma unroll
    for (int off = 32; off; off >>= 1)
        m = fmaxf(m, __shfl_xor(m, off));
    if ((tid & 63) == 0) s_w[tid >> 6] = m;
    __syncthreads();
    if (tid == 0) {
        s_cm = fmaxf(fmaxf(s_w[0], s_w[1]), fmaxf(s_w[2], s_w[3]));
        ws_max[blockIdx.x] = s_cm;
    }
    __syncthreads();
    const float cm = s_cm;

    // ---- sweep 2: adaptive collect (cache-hot re-read of own chunk) ----
    float2* seg = ws_cand + (size_t)blockIdx.x * SEG;
    float d = 3.25f * tt;
    float T = cm - d;
    unsigned int cnt = 0;
    const int nelem = (end - base) * 4;
    for (int it = 0; it < 8; ++it) {
        T = cm - d;
        __syncthreads();
        if (tid == 0) s_cnt = 0u;
        __syncthreads();
        int j = base + tid;
        for (; j + 768 < end; j += 1024) {
            float4 v0 = in4[j];
            float4 v1 = in4[j + 256];
            float4 v2 = in4[j + 512];
            float4 v3 = in4[j + 768];
            const float4 vv[4] = {v0, v1, v2, v3};
            #pragma unroll
            for (int u = 0; u < 4; ++u) {
                const float xs[4] = {vv[u].x, vv[u].y, vv[u].z, vv[u].w};
                #pragma unroll
                for (int c2 = 0; c2 < 4; ++c2) {
                    if (xs[c2] >= T) {
                        unsigned int slot = atomicAdd(&s_cnt, 1u);
                        if (slot < (unsigned)SEG) {
                            float2 p;
                            p.x = xs[c2];
                            p.y = __uint_as_float((unsigned)(4 * (j + u * 256) + c2));
                            seg[slot] = p;
                        }
                    }
                }
            }
        }
        for (; j < end; j += 256) {
            float4 v = in4[j];
            const float xs[4] = {v.x, v.y, v.z, v.w};
            #pragma unroll
            for (int c2 = 0; c2 < 4; ++c2) {
                if (xs[c2] >= T) {
                    unsigned int slot = atomicAdd(&s_cnt, 1u);
                    if (slot < (unsigned)SEG) {
                        float2 p;
                        p.x = xs[c2];
                        p.y = __uint_as_float((unsigned)(4 * j + c2));
                        seg[slot] = p;
                    }
                }
            }
        }
        __syncthreads();
        cnt = s_cnt;
        __syncthreads();
        if (cnt > (unsigned)SEG)      { if (it < 7) { d *= 0.8f; continue; } break; }
        if (cnt < (unsigned)MINSTORE && nelem > MINSTORE)
                                      { if (it < 7) { d *= 1.6f; continue; } break; }
        break;
    }
    if (tid == 0) {
        ws_cnt[blockIdx.x] = cnt;                   // > SEG flags overflow
        ws_thr[blockIdx.x] = T + 2.f * dmarg(T);    // recorded floor (upper-biased)
    }
}

// ---------------- Kernel B: per-row select (wave-level exact top-64) --------
__global__ __launch_bounds__(1024) void k_select(
        const float* __restrict__ in, float* __restrict__ out,
        const unsigned int* __restrict__ ws_cnt, const float* __restrict__ ws_max,
        const float* __restrict__ ws_thr, const float2* __restrict__ ws_cand,
        const float* __restrict__ tempP, const int* __restrict__ topkP,
        const float* __restrict__ toppP, int V, int nv4) {
    __shared__ float s_cv[CAP];
    __shared__ unsigned int s_ci[CAP];
    __shared__ ull s_lists[16][64];
    __shared__ unsigned int s_cnt;
    __shared__ float s_p[KMAX];
    __shared__ int s_kp;

    const int row = blockIdx.x;
    const int tid = (int)threadIdx.x;
    const int nthr = (int)blockDim.x;

    const float t = tempP[0];
    const bool doT = (t > 0.f);
    const float tt = doT ? t : 1.f;
    int topk = topkP[0];
    if (topk < 0 || topk > V) topk = 0;
    const float topp = toppP[0];
    const int kwant = (topk > 0) ? min(topk, KMAX) : KMAX;

    // row max, recorded-threshold floor, overflow check (original space)
    float M = NEG_INF;
    float Tfloor = NEG_INF;
    bool overflow = false;
    #pragma unroll
    for (int c = 0; c < NCHUNK; ++c) {
        M = fmaxf(M, ws_max[row * NCHUNK + c]);
        Tfloor = fmaxf(Tfloor, ws_thr[row * NCHUNK + c]);
        if (ws_cnt[row * NCHUNK + c] > (unsigned)SEG) overflow = true;
    }

    // gather ladder; attempt 2 (= Tfloor) guaranteed >= MINSTORE candidates
    unsigned int cnt = 0;
    bool ok = false;
    if (!overflow) {
        for (int attempt = 0; attempt < 3 && !ok; ++attempt) {
            const float T_att = (attempt == 0) ? fmaxf(M - 2.5f * tt, Tfloor)
                              : (attempt == 1) ? fmaxf(M - 3.25f * tt, Tfloor)
                              : Tfloor;
            const float Tcmp = T_att - dmarg(T_att);
            __syncthreads();
            if (tid == 0) s_cnt = 0u;
            __syncthreads();
            for (int c = 0; c < NCHUNK; ++c) {
                const int cc = (int)ws_cnt[row * NCHUNK + c];
                const float2* seg = ws_cand + (size_t)(row * NCHUNK + c) * SEG;
                for (int j = tid; j < cc; j += nthr) {
                    float2 p = seg[j];
                    if (p.x >= Tcmp) {
                        unsigned int slot = atomicAdd(&s_cnt, 1u);
                        if (slot < (unsigned)CAP) {
                            s_cv[slot] = p.x;
                            s_ci[slot] = __float_as_uint(p.y);
                        }
                    }
                }
            }
            __syncthreads();
            cnt = s_cnt;
            __syncthreads();
            ok = (cnt >= (unsigned)kwant && cnt <= (unsigned)CAP);
        }
    }

    // safety net (structurally unreachable): full-row adaptive collect
    if (!ok) {
        const float4* in4 = (const float4*)in + (size_t)row * nv4;
        float dcut = (cnt > (unsigned)CAP) ? 1.0f * tt : 4.5f * tt;
        for (int round = 0; round < 14; ++round) {
            if (tid == 0) s_cnt = 0u;
            __syncthreads();
            const float T = M - dcut;
            for (int i = tid; i < nv4; i += nthr) {
                float4 v = in4[i];
                const float xs[4] = {v.x, v.y, v.z, v.w};
                #pragma unroll
                for (int c2 = 0; c2 < 4; ++c2) {
                    if (xs[c2] >= T) {
                        unsigned int slot = atomicAdd(&s_cnt, 1u);
                        if (slot < (unsigned)CAP) {
                            s_cv[slot] = xs[c2];
                            s_ci[slot] = (unsigned int)(4 * i + c2);
                        }
                    }
                }
            }
            __syncthreads();
            cnt = s_cnt;
            __syncthreads();
            if (cnt >= (unsigned)kwant && cnt <= (unsigned)CAP) break;
            if (round == 13) break;
            dcut = (cnt < (unsigned)kwant) ? (dcut * 2.0f) : (dcut * 0.4f);
        }
    }
    const int ncand = (int)min(cnt, (unsigned)CAP);

    // ---- wave-level exact top-64 in SCALED space ----
    // key = (fkey(x/t) << 32) | ~idx : u64-desc == (scaled desc, idx asc),
    // identical tie semantics to the proven LDS sort (fkey bijective).
    const int wid = tid >> 6;
    const int lane = tid & 63;
    const int per = (ncand + 15) >> 4;            // share per wave (<= 256)
    const int b0 = wid * per;
    const int b1 = min(b0 + per, ncand);
    ull run = 0ull;                                // sentinel: below all reals
    for (int b = b0; b < b1; b += 64) {
        int s = b + lane;
        ull k = 0ull;
        if (s < b1) {
            float sv = doT ? (s_cv[s] / t) : s_cv[s];  // same f32 div as numpy
            k = ((ull)fkey(sv) << 32) | (ull)(~s_ci[s]);
        }
        k = sort64_desc(k, lane);
        if (b == b0) {
            run = k;
        } else {
            ull rev = __shfl(k, 63 - lane, 64);    // reversed chunk (asc)
            run = (run > rev) ? run : rev;         // bitonic top-half
            run = clean64_desc(run, lane);
        }
    }
    s_lists[wid][lane] = run;
    __syncthreads();
    #pragma unroll
    for (int half = 8; half >= 1; half >>= 1) {
        if (wid < half) {
            ull a = s_lists[wid][lane];
            ull bb = s_lists[wid + half][63 - lane];
            ull c = (a > bb) ? a : bb;
            c = clean64_desc(c, lane);
            s_lists[wid][lane] = c;
        }
        __syncthreads();
    }
    if (wid == 0) {
        ull k = s_lists[0][lane];
        s_cv[lane] = unkey((unsigned)(k >> 32));            // scaled value
        s_ci[lane] = ~(unsigned)(k & 0xFFFFFFFFull);        // token index
    }
    __syncthreads();

    if (tid == 0) s_kp = tail_select(s_cv, s_p, ncand, kwant, topk, topp);
    __syncthreads();

    if (tid < s_kp) {
        unsigned int tok = s_ci[tid];
        if (tok < (unsigned int)V)
            out[(size_t)row * V + tok] = s_p[tid];
    }
}

// ---------------- monolithic fallback (R7-proven, scaled space) ----------------
__global__ __launch_bounds__(1024) void k_row_mono(
        const float* __restrict__ in, float* __restrict__ out,
        const float* __restrict__ tempP, const int* __restrict__ topkP,
        const float* __restrict__ toppP, int V, int nv4) {
    __shared__ float s_red[1024];
    __shared__ float s_cv[CAP];
    __shared__ unsigned int s_ci[CAP];
    __shared__ unsigned int s_cnt;
    __shared__ float s_p[KMAX];
    __shared__ int s_kp;

    const int row = blockIdx.x;
    const int tid = (int)threadIdx.x;
    const int nthr = (int)blockDim.x;

    const float t = tempP[0];
    const bool doT = (t > 0.f);
    int topk = topkP[0];
    if (topk < 0 || topk > V) topk = 0;
    const float topp = toppP[0];

    const float4* in4 = (const float4*)in + (size_t)row * nv4;
    float4* out4 = (float4*)out + (size_t)row * nv4;
    float m = NEG_INF;
    for (int i = tid; i < nv4; i += nthr) {
        float4 v = in4[i];
        out4[i] = make_float4(0.f, 0.f, 0.f, 0.f);
        float a = doT ? v.x / t : v.x;
        float b = doT ? v.y / t : v.y;
        float c = doT ? v.z / t : v.z;
        float d = doT ? v.w / t : v.w;
        m = fmaxf(m, fmaxf(fmaxf(a, b), fmaxf(c, d)));
    }
    s_red[tid] = m;
    __syncthreads();
    for (int s = 512; s > 0; s >>= 1) {
        if (tid < s) s_red[tid] = fmaxf(s_red[tid], s_red[tid + s]);
        __syncthreads();
    }
    const float M = s_red[0];
    __syncthreads();

    const int kwant = (topk > 0) ? min(topk, KMAX) : KMAX;
    float dcut = 2.5f;
    unsigned int cnt = 0;
    for (int round = 0; round < 14; ++round) {
        if (tid == 0) s_cnt = 0u;
        __syncthreads();
        const float T = M - dcut;
        for (int i = tid; i < nv4; i += nthr) {
            float4 v = in4[i];
            float xs[4];
            xs[0] = doT ? v.x / t : v.x;
            xs[1] = doT ? v.y / t : v.y;
            xs[2] = doT ? v.z / t : v.z;
            xs[3] = doT ? v.w / t : v.w;
            #pragma unroll
            for (int c2 = 0; c2 < 4; ++c2) {
                if (xs[c2] >= T) {
                    unsigned int slot = atomicAdd(&s_cnt, 1u);
                    if (slot < (unsigned)CAP) {
                        s_cv[slot] = xs[c2];
                        s_ci[slot] = (unsigned int)(4 * i + c2);
                    }
                }
            }
        }
        __syncthreads();
        cnt = s_cnt;
        __syncthreads();
        if (cnt >= (unsigned)kwant && cnt <= (unsigned)CAP) break;
        if (round == 13) break;
        dcut = (cnt < (unsigned)kwant) ? (dcut * 2.0f) : (dcut * 0.4f);
    }
    const int ncand = (int)min(cnt, (unsigned)CAP);

    int sortn = 128;
    while (sortn < ncand) sortn <<= 1;
    for (int s = ncand + tid; s < sortn; s += nthr) {
        s_cv[s] = NEG_INF;
        s_ci[s] = 0xFFFFFFFFu;
    }
    __syncthreads();
    bitonic_sort(s_cv, s_ci, sortn, tid, nthr);

    if (tid == 0) s_kp = tail_select(s_cv, s_p, ncand, kwant, topk, topp);
    __syncthreads();

    if (tid < s_kp) {
        unsigned int tok = s_ci[tid];
        if (tok < (unsigned int)V)
            out[(size_t)row * V + tok] = s_p[tid];
    }
}

extern "C" void kernel_launch(void* const* d_in, const int* in_sizes, int n_in,
                              void* d_out, int out_size, void* d_ws, size_t ws_size,
                              hipStream_t stream) {
    const float* in = (const float*)d_in[0];
    const float* tempP = (const float*)d_in[2];
    const int* topkP = (const int*)d_in[3];
    const float* toppP = (const float*)d_in[4];
    float* out = (float*)d_out;

    int B = (n_in > 1 && in_sizes[1] > 0) ? in_sizes[1] : 128;
    int V = in_sizes[0] / B;
    int nv4 = V / 4;
    const int BN = B * NCHUNK;

    // ws: cnt (BN u32) | cmax (BN f32) | thr (BN f32) | cand (BN*SEG float2)
    const size_t need = (size_t)BN * 12 + (size_t)BN * SEG * 8;
    if (ws_size >= need) {
        unsigned int* ws_cnt = (unsigned int*)d_ws;
        float* ws_max = (float*)((char*)d_ws + (size_t)BN * 4);
        float* ws_thr = (float*)((char*)d_ws + (size_t)BN * 8);
        float2* ws_cand = (float2*)((char*)d_ws + (size_t)BN * 12);
        k_stream<<<BN, 256, 0, stream>>>(in, out, ws_cnt, ws_max, ws_thr,
                                         ws_cand, tempP, nv4);
        k_select<<<B, 1024, 0, stream>>>(in, out, ws_cnt, ws_max, ws_thr,
                                         ws_cand, tempP, topkP, toppP, V, nv4);
    } else {
        k_row_mono<<<B, 1024, 0, stream>>>(in, out, tempP, topkP, toppP, V, nv4);
    }
}

// Round 14
// 76.521 us; speedup vs baseline: 2.4715x; 1.1937x over previous
//
#include <hip/hip_runtime.h>
#include <cstdint>
#include <cstddef>
#include <math.h>

#define CAP 4096        // fallback path LDS size
#define KMAX 64
#define NCHUNK 16
#define LCAP 768        // per-chunk LDS candidate buffer
#define NEG_INF (-3.402823466e+38f)

typedef float v4f __attribute__((ext_vector_type(4)));
typedef unsigned long long ull;

// monotonic bijective f32 <-> u32 order keys
__device__ __forceinline__ unsigned int fkey(float f) {
    unsigned int u = __float_as_uint(f);
    return (u & 0x80000000u) ? ~u : (u | 0x80000000u);
}
__device__ __forceinline__ float unkey(unsigned int k) {
    unsigned int u = (k & 0x80000000u) ? (k & 0x7FFFFFFFu) : ~k;
    return __uint_as_float(u);
}

// margin covering f32 div rounding at threshold boundaries (scaled-tie safety)
__device__ __forceinline__ float dmarg(float T) {
    return fabsf(T) * 6e-7f + 1e-30f;
}

// ---- wave-level bitonic primitives (64 lanes, u64 keys, DESC) — R13-proven ----
__device__ __forceinline__ ull sort64_desc(ull key, int lane) {
    #pragma unroll
    for (int size = 2; size <= 64; size <<= 1) {
        #pragma unroll
        for (int stride = size >> 1; stride > 0; stride >>= 1) {
            ull other = __shfl_xor(key, stride, 64);
            bool lower = ((lane & stride) == 0);
            bool descBlk = ((lane & size) == 0);
            bool keepMax = (descBlk == lower);
            bool gt = key > other;
            key = (keepMax == gt) ? key : other;
        }
    }
    return key;
}
__device__ __forceinline__ ull clean64_desc(ull key, int lane) {
    #pragma unroll
    for (int stride = 32; stride > 0; stride >>= 1) {
        ull other = __shfl_xor(key, stride, 64);
        bool lower = ((lane & stride) == 0);
        bool gt = key > other;
        key = (lower == gt) ? key : other;
    }
    return key;
}

// thread-0 serial tail (f32-faithful, bit-exact vs gold since R7)
__device__ __forceinline__ int tail_select(
        const float* s_cv, float* s_p, int ncand, int kwant, int topk,
        float topp) {
    int kp = 0;
    if (ncand > 0) {
        int klim = min(kwant, ncand);
        if (topk > 0 && ncand >= kwant) {
            const float kth = s_cv[kwant - 1];
            while (klim < ncand && klim < KMAX && s_cv[klim] == kth) klim++;
        }
        const float sv0 = s_cv[0];
        float e[KMAX];
        for (int j = 0; j < klim; ++j)
            e[j] = (float)exp((double)(s_cv[j] - sv0));
        float r[8] = {0.f, 0.f, 0.f, 0.f, 0.f, 0.f, 0.f, 0.f};
        for (int i = 0; i < 128; i += 8)
            #pragma unroll
            for (int j2 = 0; j2 < 8; ++j2) {
                int idx = i + j2;
                if (idx < klim) r[j2] = r[j2] + e[idx];
            }
        const float S = ((r[0] + r[1]) + (r[2] + r[3])) +
                        ((r[4] + r[5]) + (r[6] + r[7]));
        if (topp > 0.f) {
            float cdf = 0.f;
            for (int j = 0; j < klim; ++j) {
                if (j > 0 && cdf > topp) break;
                kp++;
                cdf = cdf + (float)(e[j] / S);
            }
        } else {
            kp = klim;
        }
        float D = 0.f;
        for (int j = 0; j < kp; ++j) D = D + e[j];
        if (!(D > 0.f)) D = 1.f;
        for (int j = 0; j < kp; ++j) s_p[j] = e[j] / D;
    }
    return kp;
}

// LDS bitonic sort (fallback paths only): value desc, index asc
__device__ __forceinline__ void bitonic_sort(
        float* s_cv, unsigned int* s_ci, int sortn, int tid, int nthr) {
    for (unsigned int size = 2; size <= (unsigned)sortn; size <<= 1) {
        for (unsigned int stride = size >> 1; stride > 0; stride >>= 1) {
            for (int i = tid; i < sortn / 2; i += nthr) {
                unsigned int ui = (unsigned int)i;
                unsigned int pos = 2u * ui - (ui & (stride - 1u));
                unsigned int a = pos, b = pos + stride;
                float va = s_cv[a], vb = s_cv[b];
                unsigned int ia = s_ci[a], ib = s_ci[b];
                bool aBeforeB = (va > vb) || (va == vb && ia < ib);
                bool bBeforeA = (vb > va) || (vb == va && ib < ia);
                bool descBlock = ((pos & size) == 0u);
                bool doSwap = descBlock ? bBeforeA : aBeforeB;
                if (doSwap) {
                    s_cv[a] = vb; s_cv[b] = va;
                    s_ci[a] = ib; s_ci[b] = ia;
                }
            }
            __syncthreads();
        }
    }
}

// ---------------- Kernel A: stream + per-chunk exact top-64 ----------------
// Sweep 1: zero output (NT) + chunk max (original space, ILP-4).
// Sweep 2 (L3-hot, typically ONE pass): collect {x >= cmax-d} into LDS,
// d in [counts 64..LCAP] via x0.65 / x1.7 retries.
// Then: block-wide exact top-64 by SCALED key, written sorted to ws.
__global__ __launch_bounds__(256) void k_stream(
        const float* __restrict__ in, float* __restrict__ out,
        ull* __restrict__ ws_keys, float* __restrict__ ws_max,
        unsigned int* __restrict__ ws_flag, const float* __restrict__ tempP,
        int nv4) {
    __shared__ float s_w[4];
    __shared__ float s_cm;
    __shared__ unsigned int s_cnt;
    __shared__ float2 s_ent[LCAP];
    __shared__ ull s_lists[4][64];

    const int row = blockIdx.x / NCHUNK;
    const int chunk = blockIdx.x % NCHUNK;
    const int c4 = (nv4 + NCHUNK - 1) / NCHUNK;
    const int base = chunk * c4;
    const int end = min(nv4, base + c4);
    const int tid = (int)threadIdx.x;
    const int wid = tid >> 6, lane = tid & 63;
    const float t = tempP[0];
    const bool doT = (t > 0.f);
    const float tt = doT ? t : 1.f;

    const float4* in4 = (const float4*)in + (size_t)row * nv4;
    float4* out4 = (float4*)out + (size_t)row * nv4;

    // ---- sweep 1 ----
    float m = NEG_INF;
    const v4f z4 = {0.f, 0.f, 0.f, 0.f};
    int i = base + tid;
    for (; i + 768 < end; i += 1024) {
        float4 v0 = in4[i];
        float4 v1 = in4[i + 256];
        float4 v2 = in4[i + 512];
        float4 v3 = in4[i + 768];
        __builtin_nontemporal_store(z4, (v4f*)(out4 + i));
        __builtin_nontemporal_store(z4, (v4f*)(out4 + i + 256));
        __builtin_nontemporal_store(z4, (v4f*)(out4 + i + 512));
        __builtin_nontemporal_store(z4, (v4f*)(out4 + i + 768));
        float m0 = fmaxf(fmaxf(v0.x, v0.y), fmaxf(v0.z, v0.w));
        float m1 = fmaxf(fmaxf(v1.x, v1.y), fmaxf(v1.z, v1.w));
        float m2 = fmaxf(fmaxf(v2.x, v2.y), fmaxf(v2.z, v2.w));
        float m3 = fmaxf(fmaxf(v3.x, v3.y), fmaxf(v3.z, v3.w));
        m = fmaxf(m, fmaxf(fmaxf(m0, m1), fmaxf(m2, m3)));
    }
    for (; i < end; i += 256) {
        float4 v = in4[i];
        __builtin_nontemporal_store(z4, (v4f*)(out4 + i));
        m = fmaxf(m, fmaxf(fmaxf(v.x, v.y), fmaxf(v.z, v.w)));
    }
    #pragma unroll
    for (int off = 32; off; off >>= 1)
        m = fmaxf(m, __shfl_xor(m, off));
    if ((tid & 63) == 0) s_w[tid >> 6] = m;
    __syncthreads();
    if (tid == 0) {
        s_cm = fmaxf(fmaxf(s_w[0], s_w[1]), fmaxf(s_w[2], s_w[3]));
        ws_max[blockIdx.x] = s_cm;
    }
    __syncthreads();
    const float cm = s_cm;

    // ---- sweep 2: collect into LDS, typically one pass ----
    const int nelem = (end - base) * 4;
    const int minneed = min(64, nelem);
    float d = 2.2f * tt;
    unsigned int cnt = 0;
    for (int it = 0; it < 5; ++it) {
        const float T = cm - d;
        const float Tc = T - 2.f * dmarg(T);   // scaled-tie guard
        __syncthreads();
        if (tid == 0) s_cnt = 0u;
        __syncthreads();
        int j = base + tid;
        for (; j + 768 < end; j += 1024) {
            float4 v0 = in4[j];
            float4 v1 = in4[j + 256];
            float4 v2 = in4[j + 512];
            float4 v3 = in4[j + 768];
            const float4 vv[4] = {v0, v1, v2, v3};
            #pragma unroll
            for (int u = 0; u < 4; ++u) {
                const float xs[4] = {vv[u].x, vv[u].y, vv[u].z, vv[u].w};
                #pragma unroll
                for (int c2 = 0; c2 < 4; ++c2) {
                    if (xs[c2] >= Tc) {
                        unsigned int slot = atomicAdd(&s_cnt, 1u);
                        if (slot < (unsigned)LCAP) {
                            float2 p;
                            p.x = xs[c2];
                            p.y = __uint_as_float((unsigned)(4 * (j + u * 256) + c2));
                            s_ent[slot] = p;
                        }
                    }
                }
            }
        }
        for (; j < end; j += 256) {
            float4 v = in4[j];
            const float xs[4] = {v.x, v.y, v.z, v.w};
            #pragma unroll
            for (int c2 = 0; c2 < 4; ++c2) {
                if (xs[c2] >= Tc) {
                    unsigned int slot = atomicAdd(&s_cnt, 1u);
                    if (slot < (unsigned)LCAP) {
                        float2 p;
                        p.x = xs[c2];
                        p.y = __uint_as_float((unsigned)(4 * j + c2));
                        s_ent[slot] = p;
                    }
                }
            }
        }
        __syncthreads();
        cnt = s_cnt;
        __syncthreads();
        if (cnt > (unsigned)LCAP)        { if (it < 4) { d *= 0.65f; continue; } }
        else if ((int)cnt < minneed)     { if (it < 4) { d *= 1.7f;  continue; } }
        break;
    }
    const bool ok = (cnt <= (unsigned)LCAP) && ((int)cnt >= minneed);
    const int ncap = (int)min(cnt, (unsigned)LCAP);

    // ---- exact top-64 by scaled key (wave bitonic, 3 batches/wave) ----
    ull run = 0ull;
    #pragma unroll
    for (int b = 0; b < 3; ++b) {
        int s = wid * (3 * 64) + b * 64 + lane;
        ull k = 0ull;
        if (s < ncap) {
            float2 p = s_ent[s];
            float sv = doT ? (p.x / t) : p.x;       // same f32 div as numpy
            k = ((ull)fkey(sv) << 32) | (ull)(~__float_as_uint(p.y));
        }
        k = sort64_desc(k, lane);
        if (b == 0) {
            run = k;
        } else {
            ull rev = __shfl(k, 63 - lane, 64);
            run = (run > rev) ? run : rev;
            run = clean64_desc(run, lane);
        }
    }
    s_lists[wid][lane] = run;
    __syncthreads();
    if (wid < 2) {
        ull a = s_lists[wid][lane];
        ull bb = s_lists[wid + 2][63 - lane];
        ull c = (a > bb) ? a : bb;
        c = clean64_desc(c, lane);
        s_lists[wid][lane] = c;
    }
    __syncthreads();
    if (wid == 0) {
        ull a = s_lists[0][lane];
        ull bb = s_lists[1][63 - lane];
        ull c = (a > bb) ? a : bb;
        c = clean64_desc(c, lane);
        ws_keys[(size_t)blockIdx.x * 64 + lane] = c;
    }
    if (tid == 0) ws_flag[blockIdx.x] = ok ? 0u : 1u;
}

// ---------------- Kernel B: merge 16 sorted lists + tail + scatter ----------
__global__ __launch_bounds__(1024) void k_select(
        const float* __restrict__ in, float* __restrict__ out,
        const ull* __restrict__ ws_keys, const float* __restrict__ ws_max,
        const unsigned int* __restrict__ ws_flag,
        const float* __restrict__ tempP, const int* __restrict__ topkP,
        const float* __restrict__ toppP, int V, int nv4) {
    __shared__ ull s_lists[16][64];
    __shared__ float s_cv[CAP];
    __shared__ unsigned int s_ci[CAP];
    __shared__ unsigned int s_cnt;
    __shared__ float s_p[KMAX];
    __shared__ int s_kp;
    __shared__ int s_nc;

    const int row = blockIdx.x;
    const int tid = (int)threadIdx.x;
    const int nthr = (int)blockDim.x;
    const int wid = tid >> 6, lane = tid & 63;

    const float t = tempP[0];
    const bool doT = (t > 0.f);
    const float tt = doT ? t : 1.f;
    int topk = topkP[0];
    if (topk < 0 || topk > V) topk = 0;
    const float topp = toppP[0];
    const int kwant = (topk > 0) ? min(topk, KMAX) : KMAX;

    bool overflow = false;
    float M = NEG_INF;
    #pragma unroll
    for (int c = 0; c < NCHUNK; ++c) {
        if (ws_flag[row * NCHUNK + c] != 0u) overflow = true;
        M = fmaxf(M, ws_max[row * NCHUNK + c]);
    }

    int ncand;
    if (!overflow) {
        // fast path: merge 16 sorted top-64 lists
        if (wid < 16)
            s_lists[wid][lane] = ws_keys[(size_t)(row * NCHUNK + wid) * 64 + lane];
        __syncthreads();
        #pragma unroll
        for (int half = 8; half >= 1; half >>= 1) {
            if (wid < half) {
                ull a = s_lists[wid][lane];
                ull bb = s_lists[wid + half][63 - lane];
                ull c = (a > bb) ? a : bb;
                c = clean64_desc(c, lane);
                s_lists[wid][lane] = c;
            }
            __syncthreads();
        }
        if (wid == 0) {
            ull k = s_lists[0][lane];
            s_cv[lane] = unkey((unsigned)(k >> 32));       // scaled value
            s_ci[lane] = ~(unsigned)(k & 0xFFFFFFFFull);   // token index
            unsigned long long bal = __ballot(k != 0ull);
            if (lane == 0) s_nc = (int)__popcll(bal);
        }
        __syncthreads();
        ncand = s_nc;
    } else {
        // safety net: full-row adaptive collect + LDS sort (R13-proven)
        const float4* in4 = (const float4*)in + (size_t)row * nv4;
        unsigned int cnt = 0;
        float dcut = 3.0f * tt;
        for (int round = 0; round < 14; ++round) {
            if (tid == 0) s_cnt = 0u;
            __syncthreads();
            const float T = M - dcut;
            for (int i2 = tid; i2 < nv4; i2 += nthr) {
                float4 v = in4[i2];
                const float xs[4] = {v.x, v.y, v.z, v.w};
                #pragma unroll
                for (int c2 = 0; c2 < 4; ++c2) {
                    if (xs[c2] >= T) {
                        unsigned int slot = atomicAdd(&s_cnt, 1u);
                        if (slot < (unsigned)CAP) {
                            s_cv[slot] = xs[c2];
                            s_ci[slot] = (unsigned int)(4 * i2 + c2);
                        }
                    }
                }
            }
            __syncthreads();
            cnt = s_cnt;
            __syncthreads();
            if (cnt >= (unsigned)kwant && cnt <= (unsigned)CAP) break;
            if (round == 13) break;
            dcut = (cnt < (unsigned)kwant) ? (dcut * 2.0f) : (dcut * 0.4f);
        }
        ncand = (int)min(cnt, (unsigned)CAP);
        if (doT) {
            for (int j = tid; j < ncand; j += nthr) s_cv[j] = s_cv[j] / t;
        }
        int sortn = 128;
        while (sortn < ncand) sortn <<= 1;
        for (int s = ncand + tid; s < sortn; s += nthr) {
            s_cv[s] = NEG_INF;
            s_ci[s] = 0xFFFFFFFFu;
        }
        __syncthreads();
        bitonic_sort(s_cv, s_ci, sortn, tid, nthr);
    }

    if (tid == 0) s_kp = tail_select(s_cv, s_p, ncand, kwant, topk, topp);
    __syncthreads();

    if (tid < s_kp) {
        unsigned int tok = s_ci[tid];
        if (tok < (unsigned int)V)
            out[(size_t)row * V + tok] = s_p[tid];
    }
}

// ---------------- monolithic fallback (R7-proven, scaled space) -------------
__global__ __launch_bounds__(1024) void k_row_mono(
        const float* __restrict__ in, float* __restrict__ out,
        const float* __restrict__ tempP, const int* __restrict__ topkP,
        const float* __restrict__ toppP, int V, int nv4) {
    __shared__ float s_red[1024];
    __shared__ float s_cv[CAP];
    __shared__ unsigned int s_ci[CAP];
    __shared__ unsigned int s_cnt;
    __shared__ float s_p[KMAX];
    __shared__ int s_kp;

    const int row = blockIdx.x;
    const int tid = (int)threadIdx.x;
    const int nthr = (int)blockDim.x;

    const float t = tempP[0];
    const bool doT = (t > 0.f);
    int topk = topkP[0];
    if (topk < 0 || topk > V) topk = 0;
    const float topp = toppP[0];

    const float4* in4 = (const float4*)in + (size_t)row * nv4;
    float4* out4 = (float4*)out + (size_t)row * nv4;
    float m = NEG_INF;
    for (int i = tid; i < nv4; i += nthr) {
        float4 v = in4[i];
        out4[i] = make_float4(0.f, 0.f, 0.f, 0.f);
        float a = doT ? v.x / t : v.x;
        float b = doT ? v.y / t : v.y;
        float c = doT ? v.z / t : v.z;
        float d = doT ? v.w / t : v.w;
        m = fmaxf(m, fmaxf(fmaxf(a, b), fmaxf(c, d)));
    }
    s_red[tid] = m;
    __syncthreads();
    for (int s = 512; s > 0; s >>= 1) {
        if (tid < s) s_red[tid] = fmaxf(s_red[tid], s_red[tid + s]);
        __syncthreads();
    }
    const float M = s_red[0];
    __syncthreads();

    const int kwant = (topk > 0) ? min(topk, KMAX) : KMAX;
    float dcut = 2.5f;
    unsigned int cnt = 0;
    for (int round = 0; round < 14; ++round) {
        if (tid == 0) s_cnt = 0u;
        __syncthreads();
        const float T = M - dcut;
        for (int i = tid; i < nv4; i += nthr) {
            float4 v = in4[i];
            float xs[4];
            xs[0] = doT ? v.x / t : v.x;
            xs[1] = doT ? v.y / t : v.y;
            xs[2] = doT ? v.z / t : v.z;
            xs[3] = doT ? v.w / t : v.w;
            #pragma unroll
            for (int c2 = 0; c2 < 4; ++c2) {
                if (xs[c2] >= T) {
                    unsigned int slot = atomicAdd(&s_cnt, 1u);
                    if (slot < (unsigned)CAP) {
                        s_cv[slot] = xs[c2];
                        s_ci[slot] = (unsigned int)(4 * i + c2);
                    }
                }
            }
        }
        __syncthreads();
        cnt = s_cnt;
        __syncthreads();
        if (cnt >= (unsigned)kwant && cnt <= (unsigned)CAP) break;
        if (round == 13) break;
        dcut = (cnt < (unsigned)kwant) ? (dcut * 2.0f) : (dcut * 0.4f);
    }
    const int ncand = (int)min(cnt, (unsigned)CAP);

    int sortn = 128;
    while (sortn < ncand) sortn <<= 1;
    for (int s = ncand + tid; s < sortn; s += nthr) {
        s_cv[s] = NEG_INF;
        s_ci[s] = 0xFFFFFFFFu;
    }
    __syncthreads();
    bitonic_sort(s_cv, s_ci, sortn, tid, nthr);

    if (tid == 0) s_kp = tail_select(s_cv, s_p, ncand, kwant, topk, topp);
    __syncthreads();

    if (tid < s_kp) {
        unsigned int tok = s_ci[tid];
        if (tok < (unsigned int)V)
            out[(size_t)row * V + tok] = s_p[tid];
    }
}

extern "C" void kernel_launch(void* const* d_in, const int* in_sizes, int n_in,
                              void* d_out, int out_size, void* d_ws, size_t ws_size,
                              hipStream_t stream) {
    const float* in = (const float*)d_in[0];
    const float* tempP = (const float*)d_in[2];
    const int* topkP = (const int*)d_in[3];
    const float* toppP = (const float*)d_in[4];
    float* out = (float*)d_out;

    int B = (n_in > 1 && in_sizes[1] > 0) ? in_sizes[1] : 128;
    int V = in_sizes[0] / B;
    int nv4 = V / 4;
    const int BN = B * NCHUNK;

    // ws: keys (BN*64 ull) | cmax (BN f32) | flag (BN u32)
    const size_t need = (size_t)BN * 64 * 8 + (size_t)BN * 8;
    if (ws_size >= need) {
        ull* ws_keys = (ull*)d_ws;
        float* ws_max = (float*)((char*)d_ws + (size_t)BN * 64 * 8);
        unsigned int* ws_flag =
            (unsigned int*)((char*)d_ws + (size_t)BN * 64 * 8 + (size_t)BN * 4);
        k_stream<<<BN, 256, 0, stream>>>(in, out, ws_keys, ws_max, ws_flag,
                                         tempP, nv4);
        k_select<<<B, 1024, 0, stream>>>(in, out, ws_keys, ws_max, ws_flag,
                                         tempP, topkP, toppP, V, nv4);
    } else {
        k_row_mono<<<B, 1024, 0, stream>>>(in, out, tempP, topkP, toppP, V, nv4);
    }
}

// Round 15
// 66.803 us; speedup vs baseline: 2.8310x; 1.1455x over previous
//
#include <hip/hip_runtime.h>
#include <cstdint>
#include <cstddef>
#include <math.h>

#define CAP 4096        // fallback path LDS size
#define KMAX 64
#define NCHUNK 16
#define LCAP 1024       // per-chunk LDS candidate buffer
#define NEG_INF (-3.402823466e+38f)

typedef float v4f __attribute__((ext_vector_type(4)));
typedef unsigned long long ull;

// monotonic bijective f32 <-> u32 order keys
__device__ __forceinline__ unsigned int fkey(float f) {
    unsigned int u = __float_as_uint(f);
    return (u & 0x80000000u) ? ~u : (u | 0x80000000u);
}
__device__ __forceinline__ float unkey(unsigned int k) {
    unsigned int u = (k & 0x80000000u) ? (k & 0x7FFFFFFFu) : ~k;
    return __uint_as_float(u);
}

// margin covering f32 div rounding at threshold boundaries (scaled-tie safety)
__device__ __forceinline__ float dmarg(float T) {
    return fabsf(T) * 6e-7f + 1e-30f;
}

// ---- wave-level bitonic primitives (64 lanes, u64 keys, DESC) — R13-proven ----
__device__ __forceinline__ ull sort64_desc(ull key, int lane) {
    #pragma unroll
    for (int size = 2; size <= 64; size <<= 1) {
        #pragma unroll
        for (int stride = size >> 1; stride > 0; stride >>= 1) {
            ull other = __shfl_xor(key, stride, 64);
            bool lower = ((lane & stride) == 0);
            bool descBlk = ((lane & size) == 0);
            bool keepMax = (descBlk == lower);
            bool gt = key > other;
            key = (keepMax == gt) ? key : other;
        }
    }
    return key;
}
__device__ __forceinline__ ull clean64_desc(ull key, int lane) {
    #pragma unroll
    for (int stride = 32; stride > 0; stride >>= 1) {
        ull other = __shfl_xor(key, stride, 64);
        bool lower = ((lane & stride) == 0);
        bool gt = key > other;
        key = (lower == gt) ? key : other;
    }
    return key;
}

// thread-0 serial tail (f32-faithful, bit-exact vs gold since R7)
__device__ __forceinline__ int tail_select(
        const float* s_cv, float* s_p, int ncand, int kwant, int topk,
        float topp) {
    int kp = 0;
    if (ncand > 0) {
        int klim = min(kwant, ncand);
        if (topk > 0 && ncand >= kwant) {
            const float kth = s_cv[kwant - 1];
            while (klim < ncand && klim < KMAX && s_cv[klim] == kth) klim++;
        }
        const float sv0 = s_cv[0];
        float e[KMAX];
        for (int j = 0; j < klim; ++j)
            e[j] = (float)exp((double)(s_cv[j] - sv0));
        float r[8] = {0.f, 0.f, 0.f, 0.f, 0.f, 0.f, 0.f, 0.f};
        for (int i = 0; i < 128; i += 8)
            #pragma unroll
            for (int j2 = 0; j2 < 8; ++j2) {
                int idx = i + j2;
                if (idx < klim) r[j2] = r[j2] + e[idx];
            }
        const float S = ((r[0] + r[1]) + (r[2] + r[3])) +
                        ((r[4] + r[5]) + (r[6] + r[7]));
        if (topp > 0.f) {
            float cdf = 0.f;
            for (int j = 0; j < klim; ++j) {
                if (j > 0 && cdf > topp) break;
                kp++;
                cdf = cdf + (float)(e[j] / S);
            }
        } else {
            kp = klim;
        }
        float D = 0.f;
        for (int j = 0; j < kp; ++j) D = D + e[j];
        if (!(D > 0.f)) D = 1.f;
        for (int j = 0; j < kp; ++j) s_p[j] = e[j] / D;
    }
    return kp;
}

// LDS bitonic sort (fallback paths only): value desc, index asc
__device__ __forceinline__ void bitonic_sort(
        float* s_cv, unsigned int* s_ci, int sortn, int tid, int nthr) {
    for (unsigned int size = 2; size <= (unsigned)sortn; size <<= 1) {
        for (unsigned int stride = size >> 1; stride > 0; stride >>= 1) {
            for (int i = tid; i < sortn / 2; i += nthr) {
                unsigned int ui = (unsigned int)i;
                unsigned int pos = 2u * ui - (ui & (stride - 1u));
                unsigned int a = pos, b = pos + stride;
                float va = s_cv[a], vb = s_cv[b];
                unsigned int ia = s_ci[a], ib = s_ci[b];
                bool aBeforeB = (va > vb) || (va == vb && ia < ib);
                bool bBeforeA = (vb > va) || (vb == va && ib < ia);
                bool descBlock = ((pos & size) == 0u);
                bool doSwap = descBlock ? bBeforeA : aBeforeB;
                if (doSwap) {
                    s_cv[a] = vb; s_cv[b] = va;
                    s_ci[a] = ib; s_ci[b] = ia;
                }
            }
            __syncthreads();
        }
    }
}

// ---------------- Kernel A: stream + per-chunk exact top-64 ----------------
// Sweep 1: zero output (NT) + chunk max (original space, ILP-8).
// Sweep 2 (L3-hot, ~one pass): collect {x >= cmax-d} into LDS,
// d start 3.0*t, window counts [64, LCAP], retries x0.6 / x1.8.
// Then: block-wide exact top-64 by SCALED key, written sorted to ws.
__global__ __launch_bounds__(256, 8) void k_stream(
        const float* __restrict__ in, float* __restrict__ out,
        ull* __restrict__ ws_keys, float* __restrict__ ws_max,
        unsigned int* __restrict__ ws_flag, const float* __restrict__ tempP,
        int nv4) {
    __shared__ float s_w[4];
    __shared__ float s_cm;
    __shared__ unsigned int s_cnt;
    __shared__ float2 s_ent[LCAP];
    __shared__ ull s_lists[4][64];

    const int row = blockIdx.x / NCHUNK;
    const int chunk = blockIdx.x % NCHUNK;
    const int c4 = (nv4 + NCHUNK - 1) / NCHUNK;
    const int base = chunk * c4;
    const int end = min(nv4, base + c4);
    const int tid = (int)threadIdx.x;
    const int wid = tid >> 6, lane = tid & 63;
    const float t = tempP[0];
    const bool doT = (t > 0.f);
    const float tt = doT ? t : 1.f;

    const float4* in4 = (const float4*)in + (size_t)row * nv4;
    float4* out4 = (float4*)out + (size_t)row * nv4;

    // ---- sweep 1: ILP-8 ----
    float m = NEG_INF;
    const v4f z4 = {0.f, 0.f, 0.f, 0.f};
    int i = base + tid;
    for (; i + 7 * 256 < end; i += 8 * 256) {
        float4 v0 = in4[i];
        float4 v1 = in4[i + 256];
        float4 v2 = in4[i + 512];
        float4 v3 = in4[i + 768];
        float4 v4 = in4[i + 1024];
        float4 v5 = in4[i + 1280];
        float4 v6 = in4[i + 1536];
        float4 v7 = in4[i + 1792];
        #pragma unroll
        for (int u = 0; u < 8; ++u)
            __builtin_nontemporal_store(z4, (v4f*)(out4 + i + u * 256));
        float m0 = fmaxf(fmaxf(v0.x, v0.y), fmaxf(v0.z, v0.w));
        float m1 = fmaxf(fmaxf(v1.x, v1.y), fmaxf(v1.z, v1.w));
        float m2 = fmaxf(fmaxf(v2.x, v2.y), fmaxf(v2.z, v2.w));
        float m3 = fmaxf(fmaxf(v3.x, v3.y), fmaxf(v3.z, v3.w));
        float m4 = fmaxf(fmaxf(v4.x, v4.y), fmaxf(v4.z, v4.w));
        float m5 = fmaxf(fmaxf(v5.x, v5.y), fmaxf(v5.z, v5.w));
        float m6 = fmaxf(fmaxf(v6.x, v6.y), fmaxf(v6.z, v6.w));
        float m7 = fmaxf(fmaxf(v7.x, v7.y), fmaxf(v7.z, v7.w));
        m = fmaxf(m, fmaxf(fmaxf(fmaxf(m0, m1), fmaxf(m2, m3)),
                           fmaxf(fmaxf(m4, m5), fmaxf(m6, m7))));
    }
    for (; i < end; i += 256) {
        float4 v = in4[i];
        __builtin_nontemporal_store(z4, (v4f*)(out4 + i));
        m = fmaxf(m, fmaxf(fmaxf(v.x, v.y), fmaxf(v.z, v.w)));
    }
    #pragma unroll
    for (int off = 32; off; off >>= 1)
        m = fmaxf(m, __shfl_xor(m, off));
    if ((tid & 63) == 0) s_w[tid >> 6] = m;
    __syncthreads();
    if (tid == 0) {
        s_cm = fmaxf(fmaxf(s_w[0], s_w[1]), fmaxf(s_w[2], s_w[3]));
        ws_max[blockIdx.x] = s_cm;
    }
    __syncthreads();
    const float cm = s_cm;

    // ---- sweep 2: collect into LDS (typ. one pass), ILP-8 ----
    const int nelem = (end - base) * 4;
    const int minneed = min(64, nelem);
    float d = 3.0f * tt;
    unsigned int cnt = 0;
    for (int it = 0; it < 5; ++it) {
        const float T = cm - d;
        const float Tc = T - 2.f * dmarg(T);   // scaled-tie guard
        __syncthreads();
        if (tid == 0) s_cnt = 0u;
        __syncthreads();
        int j = base + tid;
        for (; j + 7 * 256 < end; j += 8 * 256) {
            float4 vv[8];
            #pragma unroll
            for (int u = 0; u < 8; ++u) vv[u] = in4[j + u * 256];
            #pragma unroll
            for (int u = 0; u < 8; ++u) {
                const float xs[4] = {vv[u].x, vv[u].y, vv[u].z, vv[u].w};
                #pragma unroll
                for (int c2 = 0; c2 < 4; ++c2) {
                    if (xs[c2] >= Tc) {
                        unsigned int slot = atomicAdd(&s_cnt, 1u);
                        if (slot < (unsigned)LCAP) {
                            float2 p;
                            p.x = xs[c2];
                            p.y = __uint_as_float((unsigned)(4 * (j + u * 256) + c2));
                            s_ent[slot] = p;
                        }
                    }
                }
            }
        }
        for (; j < end; j += 256) {
            float4 v = in4[j];
            const float xs[4] = {v.x, v.y, v.z, v.w};
            #pragma unroll
            for (int c2 = 0; c2 < 4; ++c2) {
                if (xs[c2] >= Tc) {
                    unsigned int slot = atomicAdd(&s_cnt, 1u);
                    if (slot < (unsigned)LCAP) {
                        float2 p;
                        p.x = xs[c2];
                        p.y = __uint_as_float((unsigned)(4 * j + c2));
                        s_ent[slot] = p;
                    }
                }
            }
        }
        __syncthreads();
        cnt = s_cnt;
        __syncthreads();
        if (cnt > (unsigned)LCAP)        { if (it < 4) { d *= 0.6f; continue; } }
        else if ((int)cnt < minneed)     { if (it < 4) { d *= 1.8f; continue; } }
        break;
    }
    const bool ok = (cnt <= (unsigned)LCAP) && ((int)cnt >= minneed);
    const int ncap = (int)min(cnt, (unsigned)LCAP);

    // ---- exact top-64 by scaled key (wave bitonic, dynamic batches) ----
    const int nb = (ncap + 255) >> 8;   // batches per wave (1..4)
    ull run = 0ull;
    for (int b = 0; b < nb; ++b) {
        int s = wid * (nb * 64) + b * 64 + lane;
        ull k = 0ull;
        if (s < ncap) {
            float2 p = s_ent[s];
            float sv = doT ? (p.x / t) : p.x;       // same f32 div as numpy
            k = ((ull)fkey(sv) << 32) | (ull)(~__float_as_uint(p.y));
        }
        k = sort64_desc(k, lane);
        if (b == 0) {
            run = k;
        } else {
            ull rev = __shfl(k, 63 - lane, 64);
            run = (run > rev) ? run : rev;
            run = clean64_desc(run, lane);
        }
    }
    s_lists[wid][lane] = run;
    __syncthreads();
    if (wid < 2) {
        ull a = s_lists[wid][lane];
        ull bb = s_lists[wid + 2][63 - lane];
        ull c = (a > bb) ? a : bb;
        c = clean64_desc(c, lane);
        s_lists[wid][lane] = c;
    }
    __syncthreads();
    if (wid == 0) {
        ull a = s_lists[0][lane];
        ull bb = s_lists[1][63 - lane];
        ull c = (a > bb) ? a : bb;
        c = clean64_desc(c, lane);
        ws_keys[(size_t)blockIdx.x * 64 + lane] = c;
    }
    if (tid == 0) ws_flag[blockIdx.x] = ok ? 0u : 1u;
}

// ---------------- Kernel B: merge 16 sorted lists + tail + scatter ----------
__global__ __launch_bounds__(1024) void k_select(
        const float* __restrict__ in, float* __restrict__ out,
        const ull* __restrict__ ws_keys, const float* __restrict__ ws_max,
        const unsigned int* __restrict__ ws_flag,
        const float* __restrict__ tempP, const int* __restrict__ topkP,
        const float* __restrict__ toppP, int V, int nv4) {
    __shared__ ull s_lists[16][64];
    __shared__ float s_cv[CAP];
    __shared__ unsigned int s_ci[CAP];
    __shared__ unsigned int s_cnt;
    __shared__ float s_p[KMAX];
    __shared__ int s_kp;
    __shared__ int s_nc;

    const int row = blockIdx.x;
    const int tid = (int)threadIdx.x;
    const int nthr = (int)blockDim.x;
    const int wid = tid >> 6, lane = tid & 63;

    const float t = tempP[0];
    const bool doT = (t > 0.f);
    const float tt = doT ? t : 1.f;
    int topk = topkP[0];
    if (topk < 0 || topk > V) topk = 0;
    const float topp = toppP[0];
    const int kwant = (topk > 0) ? min(topk, KMAX) : KMAX;

    bool overflow = false;
    float M = NEG_INF;
    #pragma unroll
    for (int c = 0; c < NCHUNK; ++c) {
        if (ws_flag[row * NCHUNK + c] != 0u) overflow = true;
        M = fmaxf(M, ws_max[row * NCHUNK + c]);
    }

    int ncand;
    if (!overflow) {
        // fast path: merge 16 sorted top-64 lists
        if (wid < 16)
            s_lists[wid][lane] = ws_keys[(size_t)(row * NCHUNK + wid) * 64 + lane];
        __syncthreads();
        #pragma unroll
        for (int half = 8; half >= 1; half >>= 1) {
            if (wid < half) {
                ull a = s_lists[wid][lane];
                ull bb = s_lists[wid + half][63 - lane];
                ull c = (a > bb) ? a : bb;
                c = clean64_desc(c, lane);
                s_lists[wid][lane] = c;
            }
            __syncthreads();
        }
        if (wid == 0) {
            ull k = s_lists[0][lane];
            s_cv[lane] = unkey((unsigned)(k >> 32));       // scaled value
            s_ci[lane] = ~(unsigned)(k & 0xFFFFFFFFull);   // token index
            unsigned long long bal = __ballot(k != 0ull);
            if (lane == 0) s_nc = (int)__popcll(bal);
        }
        __syncthreads();
        ncand = s_nc;
    } else {
        // safety net: full-row adaptive collect + LDS sort (R13-proven)
        const float4* in4 = (const float4*)in + (size_t)row * nv4;
        unsigned int cnt = 0;
        float dcut = 3.0f * tt;
        for (int round = 0; round < 14; ++round) {
            if (tid == 0) s_cnt = 0u;
            __syncthreads();
            const float T = M - dcut;
            for (int i2 = tid; i2 < nv4; i2 += nthr) {
                float4 v = in4[i2];
                const float xs[4] = {v.x, v.y, v.z, v.w};
                #pragma unroll
                for (int c2 = 0; c2 < 4; ++c2) {
                    if (xs[c2] >= T) {
                        unsigned int slot = atomicAdd(&s_cnt, 1u);
                        if (slot < (unsigned)CAP) {
                            s_cv[slot] = xs[c2];
                            s_ci[slot] = (unsigned int)(4 * i2 + c2);
                        }
                    }
                }
            }
            __syncthreads();
            cnt = s_cnt;
            __syncthreads();
            if (cnt >= (unsigned)kwant && cnt <= (unsigned)CAP) break;
            if (round == 13) break;
            dcut = (cnt < (unsigned)kwant) ? (dcut * 2.0f) : (dcut * 0.4f);
        }
        ncand = (int)min(cnt, (unsigned)CAP);
        if (doT) {
            for (int j = tid; j < ncand; j += nthr) s_cv[j] = s_cv[j] / t;
        }
        int sortn = 128;
        while (sortn < ncand) sortn <<= 1;
        for (int s = ncand + tid; s < sortn; s += nthr) {
            s_cv[s] = NEG_INF;
            s_ci[s] = 0xFFFFFFFFu;
        }
        __syncthreads();
        bitonic_sort(s_cv, s_ci, sortn, tid, nthr);
    }

    if (tid == 0) s_kp = tail_select(s_cv, s_p, ncand, kwant, topk, topp);
    __syncthreads();

    if (tid < s_kp) {
        unsigned int tok = s_ci[tid];
        if (tok < (unsigned int)V)
            out[(size_t)row * V + tok] = s_p[tid];
    }
}

// ---------------- monolithic fallback (R7-proven, scaled space) -------------
__global__ __launch_bounds__(1024) void k_row_mono(
        const float* __restrict__ in, float* __restrict__ out,
        const float* __restrict__ tempP, const int* __restrict__ topkP,
        const float* __restrict__ toppP, int V, int nv4) {
    __shared__ float s_red[1024];
    __shared__ float s_cv[CAP];
    __shared__ unsigned int s_ci[CAP];
    __shared__ unsigned int s_cnt;
    __shared__ float s_p[KMAX];
    __shared__ int s_kp;

    const int row = blockIdx.x;
    const int tid = (int)threadIdx.x;
    const int nthr = (int)blockDim.x;

    const float t = tempP[0];
    const bool doT = (t > 0.f);
    int topk = topkP[0];
    if (topk < 0 || topk > V) topk = 0;
    const float topp = toppP[0];

    const float4* in4 = (const float4*)in + (size_t)row * nv4;
    float4* out4 = (float4*)out + (size_t)row * nv4;
    float m = NEG_INF;
    for (int i = tid; i < nv4; i += nthr) {
        float4 v = in4[i];
        out4[i] = make_float4(0.f, 0.f, 0.f, 0.f);
        float a = doT ? v.x / t : v.x;
        float b = doT ? v.y / t : v.y;
        float c = doT ? v.z / t : v.z;
        float d = doT ? v.w / t : v.w;
        m = fmaxf(m, fmaxf(fmaxf(a, b), fmaxf(c, d)));
    }
    s_red[tid] = m;
    __syncthreads();
    for (int s = 512; s > 0; s >>= 1) {
        if (tid < s) s_red[tid] = fmaxf(s_red[tid], s_red[tid + s]);
        __syncthreads();
    }
    const float M = s_red[0];
    __syncthreads();

    const int kwant = (topk > 0) ? min(topk, KMAX) : KMAX;
    float dcut = 2.5f;
    unsigned int cnt = 0;
    for (int round = 0; round < 14; ++round) {
        if (tid == 0) s_cnt = 0u;
        __syncthreads();
        const float T = M - dcut;
        for (int i = tid; i < nv4; i += nthr) {
            float4 v = in4[i];
            float xs[4];
            xs[0] = doT ? v.x / t : v.x;
            xs[1] = doT ? v.y / t : v.y;
            xs[2] = doT ? v.z / t : v.z;
            xs[3] = doT ? v.w / t : v.w;
            #pragma unroll
            for (int c2 = 0; c2 < 4; ++c2) {
                if (xs[c2] >= T) {
                    unsigned int slot = atomicAdd(&s_cnt, 1u);
                    if (slot < (unsigned)CAP) {
                        s_cv[slot] = xs[c2];
                        s_ci[slot] = (unsigned int)(4 * i + c2);
                    }
                }
            }
        }
        __syncthreads();
        cnt = s_cnt;
        __syncthreads();
        if (cnt >= (unsigned)kwant && cnt <= (unsigned)CAP) break;
        if (round == 13) break;
        dcut = (cnt < (unsigned)kwant) ? (dcut * 2.0f) : (dcut * 0.4f);
    }
    const int ncand = (int)min(cnt, (unsigned)CAP);

    int sortn = 128;
    while (sortn < ncand) sortn <<= 1;
    for (int s = ncand + tid; s < sortn; s += nthr) {
        s_cv[s] = NEG_INF;
        s_ci[s] = 0xFFFFFFFFu;
    }
    __syncthreads();
    bitonic_sort(s_cv, s_ci, sortn, tid, nthr);

    if (tid == 0) s_kp = tail_select(s_cv, s_p, ncand, kwant, topk, topp);
    __syncthreads();

    if (tid < s_kp) {
        unsigned int tok = s_ci[tid];
        if (tok < (unsigned int)V)
            out[(size_t)row * V + tok] = s_p[tid];
    }
}

extern "C" void kernel_launch(void* const* d_in, const int* in_sizes, int n_in,
                              void* d_out, int out_size, void* d_ws, size_t ws_size,
                              hipStream_t stream) {
    const float* in = (const float*)d_in[0];
    const float* tempP = (const float*)d_in[2];
    const int* topkP = (const int*)d_in[3];
    const float* toppP = (const float*)d_in[4];
    float* out = (float*)d_out;

    int B = (n_in > 1 && in_sizes[1] > 0) ? in_sizes[1] : 128;
    int V = in_sizes[0] / B;
    int nv4 = V / 4;
    const int BN = B * NCHUNK;

    // ws: keys (BN*64 ull) | cmax (BN f32) | flag (BN u32)
    const size_t need = (size_t)BN * 64 * 8 + (size_t)BN * 8;
    if (ws_size >= need) {
        ull* ws_keys = (ull*)d_ws;
        float* ws_max = (float*)((char*)d_ws + (size_t)BN * 64 * 8);
        unsigned int* ws_flag =
            (unsigned int*)((char*)d_ws + (size_t)BN * 64 * 8 + (size_t)BN * 4);
        k_stream<<<BN, 256, 0, stream>>>(in, out, ws_keys, ws_max, ws_flag,
                                         tempP, nv4);
        k_select<<<B, 1024, 0, stream>>>(in, out, ws_keys, ws_max, ws_flag,
                                         tempP, topkP, toppP, V, nv4);
    } else {
        k_row_mono<<<B, 1024, 0, stream>>>(in, out, tempP, topkP, toppP, V, nv4);
    }
}